// Round 15
// baseline (227.562 us; speedup 1.0000x reference)
//
#include <hip/hip_runtime.h>
#include <math.h>

#define Bn 32
#define Pn 42840
#define On 64
#define NIn 8
#define Cn 11
#define ATT_N (32*56*96)
#define THRESHOLD_F 0.4f
#define THETA_F 0.1f
#define CHn 16
#define CHUNK ((Pn + CHn - 1)/CHn)
#define OC 8            /* objects per phaseB block */
#define PCn 8           /* prior chunks; Pn = 8*5355 exactly */
#define PCH (Pn/PCn)
#define DBLK 42         /* phaseD blocks per batch */
#define WPB  (DBLK*4)   /* phaseD waves per batch = 168 */
#define SEGB ((ATT_N+255)/256)   /* 672 seg blocks */
#define ABLK ((Pn/4 + 255)/256)  /* 42 phaseA blocks per batch */

// opaque register pin: read-write empty asm -> compiler cannot rematerialize
#define PINF(x) asm volatile("" : "+v"(x))

// ---- seg loss: per-block partial (no atomics) ----
__global__ void seg_kernel(const float* __restrict__ att, float* __restrict__ pseg){
  int i = blockIdx.x*256 + threadIdx.x;
  float v = 0.0f;
  if (i < ATT_N) v = fmaxf(log1pf(-att[i]), -100.0f);
  __shared__ float s[256];
  int t = threadIdx.x;
  s[t]=v; __syncthreads();
  for (int st=128; st>0; st>>=1){ if (t<st) s[t]+=s[t+st]; __syncthreads(); }
  if (t==0) pseg[blockIdx.x] = s[0];
}

// ---- phase A: 4 priors/thread; 8-object register chunks reused across priors ----
__global__ void __launch_bounds__(256, 4)
phaseA_kernel(const float* __restrict__ boxes,
              const float* __restrict__ ign,
              const float* __restrict__ priors,
              float* __restrict__ ov_prior,
              int* __restrict__ objinfo){
  __shared__ float sx1[On], sy1[On], sx2[On], sy2[On], sar[On];
  __shared__ float ix1[NIn], iy1[NIn], ix2[NIn], iy2[NIn], iar[NIn];
  int b = blockIdx.y, t = threadIdx.x;
  if (t < On){
    float4 v = ((const float4*)boxes)[b*On + t];
    sx1[t]=v.x; sy1[t]=v.y; sx2[t]=v.z; sy2[t]=v.w;
    sar[t]=(v.z-v.x)*(v.w-v.y);
  } else if (t < On+NIn){
    int o = t - On;
    float4 v = ((const float4*)ign)[b*NIn + o];
    ix1[o]=v.x; iy1[o]=v.y; ix2[o]=v.z; iy2[o]=v.w;
    iar[o]=(v.z-v.x)*(v.w-v.y);
  }
  __syncthreads();
  int p0 = (blockIdx.x*256 + t)*4;
  if (p0 >= Pn) return;              // Pn%4==0 -> all 4 valid when p0<Pn
  float px1[4], py1[4], px2[4], py2[4], pab[4];
  #pragma unroll
  for (int q=0;q<4;q++){
    float4 pc = ((const float4*)priors)[p0+q];
    px1[q]=pc.x - pc.z*0.5f; py1[q]=pc.y - pc.w*0.5f;
    px2[q]=pc.x + pc.z*0.5f; py2[q]=pc.y + pc.w*0.5f;
    pab[q]=(px2[q]-px1[q])*(py2[q]-py1[q]);
  }
  float bi[4], bu[4]; int bo[4];
  #pragma unroll
  for (int q=0;q<4;q++){ bi[q]=-1.0f; bu[q]=1.0f; bo[q]=0; }
  #pragma unroll 1
  for (int og=0; og<8; og++){
    float ox1[8],oy1[8],ox2[8],oy2[8],oar[8];
    #pragma unroll
    for (int j=0;j<8;j++){
      int o = og*8+j;
      ox1[j]=sx1[o]; oy1[j]=sy1[o]; ox2[j]=sx2[o]; oy2[j]=sy2[o]; oar[j]=sar[o];
    }
    #pragma unroll
    for (int j=0;j<8;j++){
      #pragma unroll
      for (int q=0;q<4;q++){
        float ltx=fmaxf(ox1[j],px1[q]), lty=fmaxf(oy1[j],py1[q]);
        float rbx=fminf(ox2[j],px2[q]), rby=fminf(oy2[j],py2[q]);
        float w=fmaxf(rbx-ltx,0.0f), h=fmaxf(rby-lty,0.0f);
        float inter=w*h;
        float uni=(oar[j]+pab[q])-inter;
        if (inter*bu[q] > bi[q]*uni){ bi[q]=inter; bu[q]=uni; bo[q]=og*8+j; }
      }
    }
  }
  float ii[4], iu[4];
  #pragma unroll
  for (int q=0;q<4;q++){ ii[q]=-1.0f; iu[q]=1.0f; }
  #pragma unroll
  for (int j=0;j<NIn;j++){
    float jx1=ix1[j], jy1=iy1[j], jx2=ix2[j], jy2=iy2[j], jar=iar[j];
    #pragma unroll
    for (int q=0;q<4;q++){
      float ltx=fmaxf(jx1,px1[q]), lty=fmaxf(jy1,py1[q]);
      float rbx=fminf(jx2,px2[q]), rby=fminf(jy2,py2[q]);
      float w=fmaxf(rbx-ltx,0.0f), h=fmaxf(rby-lty,0.0f);
      float inter=w*h;
      float uni=(jar+pab[q])-inter;
      if (inter*iu[q] > ii[q]*uni){ ii[q]=inter; iu[q]=uni; }
    }
  }
  size_t bp0 = (size_t)b*Pn + p0;
  float ov_[4]; int in_[4];
  #pragma unroll
  for (int q=0;q<4;q++){
    ov_[q] = bi[q]/bu[q];
    float ig = ii[q]/iu[q];
    in_[q] = bo[q] | ((ig >= THETA_F) ? 256 : 0);
  }
  *(float4*)(ov_prior + bp0) = make_float4(ov_[0],ov_[1],ov_[2],ov_[3]);
  *(int4*)(objinfo + bp0)    = make_int4(in_[0],in_[1],in_[2],in_[3]);
}

// ---- phase B: per (b,o) argmax over P; object data pinned in registers ----
__global__ void phaseB_kernel(const float* __restrict__ boxes,
                              const float* __restrict__ priors,
                              unsigned long long* __restrict__ key_obj){
  int c = blockIdx.x, og = blockIdx.y, b = blockIdx.z, t = threadIdx.x;
  float ox1[OC], oy1[OC], ox2[OC], oy2[OC], oa[OC];
  const float4* bx = (const float4*)(boxes + ((size_t)b*On + og*OC)*4);
  #pragma unroll
  for (int j=0;j<OC;j++){
    float4 v = bx[j];
    ox1[j]=v.x; oy1[j]=v.y; ox2[j]=v.z; oy2[j]=v.w;
    oa[j]=(v.z-v.x)*(v.w-v.y);
  }
  // pin object data live in VGPRs -> no per-iteration re-load/remat
  #pragma unroll
  for (int j=0;j<OC;j++){
    PINF(ox1[j]); PINF(oy1[j]); PINF(ox2[j]); PINF(oy2[j]); PINF(oa[j]);
  }
  float bi[OC], bu[OC]; unsigned bp_[OC];
  #pragma unroll
  for (int j=0;j<OC;j++){ bi[j]=-1.0f; bu[j]=1.0f; bp_[j]=0u; }
  int p0 = c*PCH;
  for (int p=p0+t; p<p0+PCH; p+=256){
    float4 pc = ((const float4*)priors)[p];
    float px1 = pc.x - pc.z*0.5f, py1 = pc.y - pc.w*0.5f;
    float px2 = pc.x + pc.z*0.5f, py2 = pc.y + pc.w*0.5f;
    float ab = (px2-px1)*(py2-py1);
    #pragma unroll
    for (int j=0;j<OC;j++){
      float ltx=fmaxf(ox1[j],px1), lty=fmaxf(oy1[j],py1);
      float rbx=fminf(ox2[j],px2), rby=fminf(oy2[j],py2);
      float w=fmaxf(rbx-ltx,0.0f), h=fmaxf(rby-lty,0.0f);
      float inter=w*h;
      float uni=(oa[j]+ab)-inter;
      if (inter*bu[j] > bi[j]*uni){ bi[j]=inter; bu[j]=uni; bp_[j]=(unsigned)p; }
    }
  }
  #pragma unroll
  for (int j=0;j<OC;j++){
    float iou = bi[j]/bu[j];               // one exact division per object
    unsigned long long key = ((unsigned long long)__float_as_uint(iou)<<32)
                           | (unsigned long long)(0xFFFFFFFFu - bp_[j]);
    #pragma unroll
    for (int d=32; d>0; d>>=1){
      unsigned long long o2 = __shfl_xor(key, d, 64);
      if (o2 > key) key = o2;
    }
    if ((t & 63) == 0)
      atomicMax(&key_obj[(size_t)b*On + og*OC + j], key);
  }
}

// ---- phase C: sequential per-batch scatter (set 1.0; last-write-wins rank) ----
__global__ void phaseC_kernel(const unsigned long long* __restrict__ key_obj,
                              float* __restrict__ ov_prior,
                              int* __restrict__ objinfo){
  int b = threadIdx.x;
  if (b >= Bn) return;
  int rank = -1;
  for (int o=0;o<On;o++){
    unsigned long long k = key_obj[(size_t)b*On+o];
    if ((unsigned)(k>>32) > 0u){            // iou > 0  <=> valid
      rank++;                               // jranks = cumsum(valid)-1
      int p = (int)(0xFFFFFFFFu - (unsigned)(k & 0xFFFFFFFFu));
      size_t bp = (size_t)b*Pn + p;
      ov_prior[bp] = 1.0f;
      objinfo[bp] = (objinfo[bp] & 256) | rank; // ascending o => overwrite == max(jr)
    }
  }
}

// ---- phase D: 4 priors/thread; per-WAVE shuffle reduce; no barriers, no atomics ----
__global__ void __launch_bounds__(256, 4)
phaseD_kernel(const float* __restrict__ odm_locs,
              const float* __restrict__ odm_scores,
              const float* __restrict__ boxes,
              const int* __restrict__ labels,
              const float* __restrict__ priors,
              const float* __restrict__ ov_prior,
              const int* __restrict__ objinfo,
              float* __restrict__ conf_neg,
              float* __restrict__ ploc,
              float* __restrict__ pconf,
              int* __restrict__ ppos){
  int b = blockIdx.y;
  int t = threadIdx.x;
  int p0 = (blockIdx.x*256 + t)*4;
  float locv = 0.0f, confpv = 0.0f; int posv = 0;
  if (p0 < Pn){                           // Pn%4==0 -> all 4 priors valid
    size_t bp0 = (size_t)b*Pn + p0;
    float4 sc4[11];
    const float4* src = (const float4*)(odm_scores + bp0*Cn);  // 16B-aligned
    #pragma unroll
    for (int i=0;i<11;i++) sc4[i] = src[i];
    int4   info4 = *(const int4*)(objinfo + bp0);
    float4 ovp4  = *(const float4*)(ov_prior + bp0);
    const float* sc = (const float*)sc4;   // constant indices only (post-unroll)
    float cn[4];
    #pragma unroll
    for (int j=0;j<4;j++){
      int info = (&info4.x)[j];
      int obj = info & 0xFF;
      bool ignored = (info & 256) != 0;
      int label = labels[b*On + obj];
      if ((&ovp4.x)[j] < THRESHOLD_F) label = 0;
      bool pos = label > 0;
      float m = sc[j*Cn];
      #pragma unroll
      for (int c=1;c<Cn;c++) m = fmaxf(m, sc[j*Cn+c]);
      float se = 0.0f, slab = 0.0f;
      #pragma unroll
      for (int c=0;c<Cn;c++){
        float v = sc[j*Cn+c];
        se += expf(v-m);
        if (c == label) slab = v;          // c is compile-time -> cndmask chain
      }
      float conf = logf(se) - (slab-m);
      cn[j] = (pos || ignored) ? 0.0f : conf;
      if (pos){
        posv += 1; confpv += conf;
        size_t bp = bp0 + j;
        float4 pc = ((const float4*)priors)[p0+j];
        float4 g  = ((const float4*)odm_locs)[bp];
        float cx = g.x*pc.z/10.0f + pc.x;
        float cy = g.y*pc.w/10.0f + pc.y;
        float w  = expf(g.z/5.0f)*pc.z;
        float h  = expf(g.w/5.0f)*pc.w;
        float dx1 = cx - w/2.0f, dy1 = cy - h/2.0f;
        float dx2 = cx + w/2.0f, dy2 = cy + h/2.0f;
        const float* gt = boxes + ((size_t)b*On + obj)*4;
        float gx1=gt[0], gy1=gt[1], gx2=gt[2], gy2=gt[3];
        float ltx=fmaxf(dx1,gx1), lty=fmaxf(dy1,gy1);
        float rbx=fminf(dx2,gx2), rby=fminf(dy2,gy2);
        float iw=fmaxf(rbx-ltx,0.0f), ih=fmaxf(rby-lty,0.0f);
        float inter=iw*ih;
        float ap=(dx2-dx1)*(dy2-dy1);
        float ag=(gx2-gx1)*(gy2-gy1);
        float iou = inter/((ap+ag)-inter);
        float cpx=(dx1+dx2)/2.0f, cpy=(dy1+dy2)/2.0f;
        float cgx=(gx1+gx2)/2.0f, cgy=(gy1+gy2)/2.0f;
        float ddx=cpx-cgx, ddy=cpy-cgy;
        float inter_diag = ddx*ddx + ddy*ddy;
        float cltx=fminf(dx1,gx1), clty=fminf(dy1,gy1);
        float crbx=fmaxf(dx2,gx2), crby=fmaxf(dy2,gy2);
        float odx=crbx-cltx, ody=crby-clty;
        float outer_diag = odx*odx + ody*ody;
        float diou = fminf(fmaxf(iou - inter_diag/outer_diag, -1.0f), 1.0f);
        locv += 1.0f - diou;
      }
    }
    *(float4*)(conf_neg + bp0) = make_float4(cn[0],cn[1],cn[2],cn[3]);
  }
  // per-wave butterfly reduction, lane 0 writes a unique slot -> zero contention
  #pragma unroll
  for (int d=32; d>0; d>>=1){
    locv   += __shfl_xor(locv,   d, 64);
    confpv += __shfl_xor(confpv, d, 64);
    posv   += __shfl_xor(posv,   d, 64);
  }
  if ((t & 63) == 0){
    int widx = b*WPB + (blockIdx.x<<2) + (t>>6);
    ploc[widx]  = locv;
    pconf[widx] = confpv;
    ppos[widx]  = posv;
  }
}

// ---- n_pos reduce ----
__global__ void npos_kernel(const int* __restrict__ ppos, int* __restrict__ n_pos){
  int b = threadIdx.x;
  if (b >= Bn) return;
  int s = 0;
  for (int w=0; w<WPB; w++) s += ppos[b*WPB + w];
  n_pos[b] = s;
}

// ---- phase E: 2-round radix select with per-bin (count,sum) ----
template<int ROUND>
__global__ void histE_kernel(const float* __restrict__ conf_neg,
                             const int* __restrict__ n_pos,
                             const unsigned* __restrict__ prefix,
                             const int* __restrict__ krem_st,
                             unsigned* __restrict__ gcnt,
                             float* __restrict__ gsum){
  int b = blockIdx.y, c = blockIdx.x, t = threadIdx.x;
  if (n_pos[b] <= 0) return;
  if (ROUND==1 && krem_st[b] < 0) return;   // K>=Pn handled in scan0
  __shared__ unsigned hc[4096];
  __shared__ float    hs[4096];
  for (int i=t;i<4096;i+=256){ hc[i]=0u; hs[i]=0.0f; }
  __syncthreads();
  unsigned pref = (ROUND==0)?0u:(prefix[b]>>20);
  const float* cn = conf_neg + (size_t)b*Pn;
  int p0 = c*CHUNK, p1 = min(Pn, p0+CHUNK);
  for (int p=p0+t; p<p1; p+=256){
    float v = cn[p];
    unsigned key = __float_as_uint(v);   // v >= 0 -> uint order == float order
    if (ROUND==0){
      unsigned d = key>>20;
      atomicAdd(&hc[d],1u); atomicAdd(&hs[d],v);
    } else {
      if ((key>>20)==pref){
        unsigned d = (key>>8)&0xFFFu;
        atomicAdd(&hc[d],1u); atomicAdd(&hs[d],v);
      }
    }
  }
  __syncthreads();
  unsigned* gc = gcnt + (size_t)b*4096;
  float*    gs = gsum + (size_t)b*4096;
  for (int i=t;i<4096;i+=256){
    if (hc[i]){ atomicAdd(&gc[i], hc[i]); atomicAdd(&gs[i], hs[i]); }
  }
}

template<int ROUND>
__global__ void scanE_kernel(const unsigned* __restrict__ gcnt,
                             const float* __restrict__ gsum,
                             const int* __restrict__ n_pos,
                             unsigned* __restrict__ prefix,
                             int* __restrict__ krem_st,
                             double* __restrict__ stop0,
                             double* __restrict__ phard){
  int b = blockIdx.x, t = threadIdx.x;
  int K = 2*n_pos[b];
  if (K <= 0){ if (ROUND==0 && t==0) phard[b] = 0.0; return; }
  if (ROUND==1 && krem_st[b] < 0) return;
  const unsigned* gc = gcnt + (size_t)b*4096;
  const float*    gs = gsum + (size_t)b*4096;
  unsigned cnt[16]; float sm[16];
  unsigned ts = 0;
  #pragma unroll
  for (int i=0;i<16;i++){ cnt[i]=gc[t*16+i]; sm[i]=gs[t*16+i]; ts+=cnt[i]; }
  __shared__ unsigned sh[256];
  __shared__ int s_sel;
  __shared__ double sd[256];
  if (t==0) s_sel = -1;
  sh[t]=ts;
  __syncthreads();
  for (int off=1; off<256; off<<=1){
    unsigned v = (t+off<256)? sh[t+off]:0u;   // read (after barrier)
    __syncthreads();
    sh[t]+=v;                                  // write
    __syncthreads();
  }
  if (ROUND==0 && K >= Pn){
    double ds=0.0;
    #pragma unroll
    for (int i=0;i<16;i++) ds += (double)sm[i];
    sd[t]=ds; __syncthreads();
    for (int st=128;st>0;st>>=1){ if(t<st) sd[t]+=sd[t+st]; __syncthreads(); }
    if (t==0){ phard[b]=sd[0]; krem_st[b]=-1; }
    return;
  }
  int krem = (ROUND==0)? K : krem_st[b];
  unsigned incl = sh[t];           // count of keys in bins >= this thread's lowest
  unsigned above = incl - ts;      // count in strictly-higher threads' bins
  if ((int)above < krem && krem <= (int)incl){
    int acc = (int)above;
    #pragma unroll
    for (int i=15;i>=0;i--){
      acc += (int)cnt[i];
      if (acc >= krem){
        unsigned sel = (unsigned)(t*16+i);
        int krem_new = krem - (acc - (int)cnt[i]);
        if (ROUND==0) prefix[b]  = sel<<20;
        else          prefix[b] |= sel<<8;
        krem_st[b] = krem_new;
        s_sel = (int)sel;
        break;
      }
    }
  }
  __syncthreads();
  int sel = s_sel;
  double ds = 0.0;
  #pragma unroll
  for (int i=0;i<16;i++){ int idx=t*16+i; if (idx > sel) ds += (double)sm[i]; }
  sd[t]=ds; __syncthreads();
  for (int st=128;st>0;st>>=1){ if(t<st) sd[t]+=sd[t+st]; __syncthreads(); }
  if (t==0){
    if (ROUND==0) stop0[b] = sd[0];
    else {
      // tie bucket approximated by its midpoint (error << absmax threshold)
      float vmid = __uint_as_float(prefix[b] | 0x80u);
      phard[b] = stop0[b] + sd[0] + (double)krem_st[b] * (double)vmid;
    }
  }
}

// ---- final combine: sum all partial arrays in doubles ----
__global__ void final_kernel(const int* __restrict__ n_pos,
                             const float* __restrict__ pseg,
                             const float* __restrict__ ploc,
                             const float* __restrict__ pconf,
                             const double* __restrict__ phard,
                             float* __restrict__ out){
  int t = threadIdx.x;
  double seg_s=0.0, loc_s=0.0, conf_s=0.0, hard_s=0.0;
  for (int i=t;i<SEGB;i+=256)     seg_s  += (double)pseg[i];
  for (int i=t;i<Bn*WPB;i+=256)   loc_s  += (double)ploc[i];
  for (int i=t;i<Bn*WPB;i+=256)   conf_s += (double)pconf[i];
  for (int i=t;i<Bn;i+=256)       hard_s += phard[i];
  int tp_s = (t < Bn) ? n_pos[t] : 0;
  __shared__ double sd[256];
  __shared__ int    si_[256];
  si_[t]=tp_s;
  sd[t]=seg_s;  __syncthreads();
  for (int st=128;st>0;st>>=1){ if(t<st){ sd[t]+=sd[t+st]; si_[t]+=si_[t+st]; } __syncthreads(); }
  double seg_t = sd[0]; int tp = si_[0];
  __syncthreads();
  sd[t]=loc_s;  __syncthreads();
  for (int st=128;st>0;st>>=1){ if(t<st) sd[t]+=sd[t+st]; __syncthreads(); }
  double loc_t = sd[0];
  __syncthreads();
  sd[t]=conf_s+hard_s; __syncthreads();
  for (int st=128;st>0;st>>=1){ if(t<st) sd[t]+=sd[t+st]; __syncthreads(); }
  double conf_t = sd[0];
  if (t==0){
    float total = (float)tp;
    float conf_loss = (float)conf_t / total;
    float loc_loss  = (float)loc_t / total;
    float seg_loss  = -(float)seg_t;
    out[0] = conf_loss + loc_loss + seg_loss;
  }
}

extern "C" void kernel_launch(void* const* d_in, const int* in_sizes, int n_in,
                              void* d_out, int out_size, void* d_ws, size_t ws_size,
                              hipStream_t stream) {
  const float* odm_locs   = (const float*)d_in[0];
  const float* odm_scores = (const float*)d_in[1];
  const float* att        = (const float*)d_in[2];
  const float* boxes      = (const float*)d_in[3];
  const int*   labels     = (const int*)d_in[4];
  const float* ign        = (const float*)d_in[5];
  const float* priors     = (const float*)d_in[6];
  float* out = (float*)d_out;

  size_t np = (size_t)Bn * Pn;
  float* ov_prior  = (float*)d_ws;                 // B*P f32
  int*   objinfo   = (int*)(ov_prior + np);        // B*P i32
  float* conf_neg  = (float*)(objinfo + np);       // B*P f32
  unsigned long long* key_obj = (unsigned long long*)(conf_neg + np); // B*O u64
  double* phard    = (double*)(key_obj + (size_t)Bn*On); // Bn f64
  int*    n_pos    = (int*)(phard + Bn);                 // B i32
  float*  pseg     = (float*)(n_pos + Bn);               // SEGB f32
  float*  ploc     = pseg + SEGB;                        // B*WPB f32
  float*  pconf    = ploc + (size_t)Bn*WPB;              // B*WPB f32
  int*    ppos     = (int*)(pconf + (size_t)Bn*WPB);     // B*WPB i32

  // radix-select scratch in the ov_prior region (dead after phaseD):
  unsigned* gcnt0 = (unsigned*)ov_prior;
  float*    gsum0 = (float*)(gcnt0 + (size_t)Bn*4096);
  unsigned* gcnt1 = (unsigned*)(gsum0 + (size_t)Bn*4096);
  float*    gsum1 = (float*)(gcnt1 + (size_t)Bn*4096);
  unsigned* prefix = (unsigned*)(gsum1 + (size_t)Bn*4096);
  int*      krem   = (int*)(prefix + Bn);
  double*   stop0  = (double*)(krem + Bn);   // 8B-aligned: 2MB+256B offset

  // only key_obj needs zeroing (atomicMax targets); partials fully written
  hipMemsetAsync(key_obj, 0, (size_t)Bn*On*8, stream);

  seg_kernel  <<<SEGB, 256, 0, stream>>>(att, pseg);
  phaseA_kernel<<<dim3(ABLK, Bn), 256, 0, stream>>>(boxes, ign, priors, ov_prior, objinfo);
  phaseB_kernel<<<dim3(PCn, On/OC, Bn), 256, 0, stream>>>(boxes, priors, key_obj);
  phaseC_kernel<<<1, 64, 0, stream>>>(key_obj, ov_prior, objinfo);
  phaseD_kernel<<<dim3(DBLK, Bn), 256, 0, stream>>>(odm_locs, odm_scores, boxes, labels,
                                                    priors, ov_prior, objinfo,
                                                    conf_neg, ploc, pconf, ppos);
  npos_kernel<<<1, 64, 0, stream>>>(ppos, n_pos);
  // ov_prior dead from here; reuse as radix scratch
  hipMemsetAsync(gcnt0, 0, 4*(size_t)Bn*4096*sizeof(unsigned), stream);
  histE_kernel<0><<<dim3(CHn, Bn), 256, 0, stream>>>(conf_neg, n_pos, prefix, krem, gcnt0, gsum0);
  scanE_kernel<0><<<Bn, 256, 0, stream>>>(gcnt0, gsum0, n_pos, prefix, krem, stop0, phard);
  histE_kernel<1><<<dim3(CHn, Bn), 256, 0, stream>>>(conf_neg, n_pos, prefix, krem, gcnt1, gsum1);
  scanE_kernel<1><<<Bn, 256, 0, stream>>>(gcnt1, gsum1, n_pos, prefix, krem, stop0, phard);
  final_kernel<<<1, 256, 0, stream>>>(n_pos, pseg, ploc, pconf, phard, out);
}

// Round 16
// 226.888 us; speedup vs baseline: 1.0030x; 1.0030x over previous
//
#include <hip/hip_runtime.h>
#include <math.h>

#define Bn 32
#define Pn 42840
#define On 64
#define NIn 8
#define Cn 11
#define ATT_N (32*56*96)
#define THRESHOLD_F 0.4f
#define THETA_F 0.1f
#define CHn 16
#define CHUNK ((Pn + CHn - 1)/CHn)
#define OC 8            /* objects per phaseB block */
#define PCn 8           /* prior chunks; Pn = 8*5355 exactly */
#define PCH (Pn/PCn)
#define DBLK 42         /* phaseD blocks per batch */
#define WPB  (DBLK*4)   /* phaseD waves per batch = 168 */
#define SEGB ((ATT_N+255)/256)   /* 672 seg blocks */
#define ABLK ((Pn/4 + 255)/256)  /* 42 phaseA blocks per batch */

// opaque register pin: read-write empty asm -> compiler cannot rematerialize
#define PINF(x) asm volatile("" : "+v"(x))

// ---- seg loss: per-block partial (no atomics) ----
__global__ void seg_kernel(const float* __restrict__ att, float* __restrict__ pseg){
  int i = blockIdx.x*256 + threadIdx.x;
  float v = 0.0f;
  if (i < ATT_N) v = fmaxf(log1pf(-att[i]), -100.0f);
  __shared__ float s[256];
  int t = threadIdx.x;
  s[t]=v; __syncthreads();
  for (int st=128; st>0; st>>=1){ if (t<st) s[t]+=s[t+st]; __syncthreads(); }
  if (t==0) pseg[blockIdx.x] = s[0];
}

// ---- phase A: 4 priors/thread; rcp-based iou (1-ulp), float tracker ----
__global__ void __launch_bounds__(256, 4)
phaseA_kernel(const float* __restrict__ boxes,
              const float* __restrict__ ign,
              const float* __restrict__ priors,
              float* __restrict__ ov_prior,
              int* __restrict__ objinfo){
  __shared__ float sx1[On], sy1[On], sx2[On], sy2[On], sar[On];
  __shared__ float ix1[NIn], iy1[NIn], ix2[NIn], iy2[NIn], iar[NIn];
  int b = blockIdx.y, t = threadIdx.x;
  if (t < On){
    float4 v = ((const float4*)boxes)[b*On + t];
    sx1[t]=v.x; sy1[t]=v.y; sx2[t]=v.z; sy2[t]=v.w;
    sar[t]=(v.z-v.x)*(v.w-v.y);
  } else if (t < On+NIn){
    int o = t - On;
    float4 v = ((const float4*)ign)[b*NIn + o];
    ix1[o]=v.x; iy1[o]=v.y; ix2[o]=v.z; iy2[o]=v.w;
    iar[o]=(v.z-v.x)*(v.w-v.y);
  }
  __syncthreads();
  int p0 = (blockIdx.x*256 + t)*4;
  if (p0 >= Pn) return;              // Pn%4==0 -> all 4 valid when p0<Pn
  float px1[4], py1[4], px2[4], py2[4], pab[4];
  #pragma unroll
  for (int q=0;q<4;q++){
    float4 pc = ((const float4*)priors)[p0+q];
    px1[q]=pc.x - pc.z*0.5f; py1[q]=pc.y - pc.w*0.5f;
    px2[q]=pc.x + pc.z*0.5f; py2[q]=pc.y + pc.w*0.5f;
    pab[q]=(px2[q]-px1[q])*(py2[q]-py1[q]);
  }
  float best[4]; int bo[4];
  #pragma unroll
  for (int q=0;q<4;q++){ best[q]=-1.0f; bo[q]=0; }
  #pragma unroll 1
  for (int og=0; og<8; og++){
    #pragma unroll
    for (int j=0;j<8;j++){
      int o = og*8+j;
      float ox1=sx1[o], oy1=sy1[o], ox2=sx2[o], oy2=sy2[o], oar=sar[o];
      #pragma unroll
      for (int q=0;q<4;q++){
        float ltx=fmaxf(ox1,px1[q]), lty=fmaxf(oy1,py1[q]);
        float rbx=fminf(ox2,px2[q]), rby=fminf(oy2,py2[q]);
        float w=fmaxf(rbx-ltx,0.0f), h=fmaxf(rby-lty,0.0f);
        float inter=w*h;
        float uni=(oar+pab[q])-inter;
        float iou = inter * __builtin_amdgcn_rcpf(uni);
        if (iou > best[q]){ best[q]=iou; bo[q]=o; }   // strict > keeps first
      }
    }
  }
  float ib[4];
  #pragma unroll
  for (int q=0;q<4;q++) ib[q]=-1.0f;
  #pragma unroll
  for (int j=0;j<NIn;j++){
    float jx1=ix1[j], jy1=iy1[j], jx2=ix2[j], jy2=iy2[j], jar=iar[j];
    #pragma unroll
    for (int q=0;q<4;q++){
      float ltx=fmaxf(jx1,px1[q]), lty=fmaxf(jy1,py1[q]);
      float rbx=fminf(jx2,px2[q]), rby=fminf(jy2,py2[q]);
      float w=fmaxf(rbx-ltx,0.0f), h=fmaxf(rby-lty,0.0f);
      float inter=w*h;
      float uni=(jar+pab[q])-inter;
      float iou = inter * __builtin_amdgcn_rcpf(uni);
      ib[q] = fmaxf(ib[q], iou);
    }
  }
  size_t bp0 = (size_t)b*Pn + p0;
  int in_[4];
  #pragma unroll
  for (int q=0;q<4;q++)
    in_[q] = bo[q] | ((ib[q] >= THETA_F) ? 256 : 0);
  *(float4*)(ov_prior + bp0) = make_float4(best[0],best[1],best[2],best[3]);
  *(int4*)(objinfo + bp0)    = make_int4(in_[0],in_[1],in_[2],in_[3]);
}

// ---- phase B: per (b,o) argmax over P; rcp-based iou, float tracker ----
__global__ void phaseB_kernel(const float* __restrict__ boxes,
                              const float* __restrict__ priors,
                              unsigned long long* __restrict__ key_obj){
  int c = blockIdx.x, og = blockIdx.y, b = blockIdx.z, t = threadIdx.x;
  float ox1[OC], oy1[OC], ox2[OC], oy2[OC], oa[OC];
  const float4* bx = (const float4*)(boxes + ((size_t)b*On + og*OC)*4);
  #pragma unroll
  for (int j=0;j<OC;j++){
    float4 v = bx[j];
    ox1[j]=v.x; oy1[j]=v.y; ox2[j]=v.z; oy2[j]=v.w;
    oa[j]=(v.z-v.x)*(v.w-v.y);
  }
  // pin object data live in VGPRs -> no per-iteration re-load/remat
  #pragma unroll
  for (int j=0;j<OC;j++){
    PINF(ox1[j]); PINF(oy1[j]); PINF(ox2[j]); PINF(oy2[j]); PINF(oa[j]);
  }
  float bb[OC]; unsigned bp_[OC];
  #pragma unroll
  for (int j=0;j<OC;j++){ bb[j]=-1.0f; bp_[j]=0u; }
  int p0 = c*PCH;
  for (int p=p0+t; p<p0+PCH; p+=256){
    float4 pc = ((const float4*)priors)[p];
    float px1 = pc.x - pc.z*0.5f, py1 = pc.y - pc.w*0.5f;
    float px2 = pc.x + pc.z*0.5f, py2 = pc.y + pc.w*0.5f;
    float ab = (px2-px1)*(py2-py1);
    #pragma unroll
    for (int j=0;j<OC;j++){
      float ltx=fmaxf(ox1[j],px1), lty=fmaxf(oy1[j],py1);
      float rbx=fminf(ox2[j],px2), rby=fminf(oy2[j],py2);
      float w=fmaxf(rbx-ltx,0.0f), h=fmaxf(rby-lty,0.0f);
      float inter=w*h;
      float uni=(oa[j]+ab)-inter;
      float iou = inter * __builtin_amdgcn_rcpf(uni);
      if (iou > bb[j]){ bb[j]=iou; bp_[j]=(unsigned)p; }  // smallest p wins ties
    }
  }
  #pragma unroll
  for (int j=0;j<OC;j++){
    unsigned long long key = ((unsigned long long)__float_as_uint(bb[j])<<32)
                           | (unsigned long long)(0xFFFFFFFFu - bp_[j]);
    #pragma unroll
    for (int d=32; d>0; d>>=1){
      unsigned long long o2 = __shfl_xor(key, d, 64);
      if (o2 > key) key = o2;
    }
    if ((t & 63) == 0)
      atomicMax(&key_obj[(size_t)b*On + og*OC + j], key);
  }
}

// ---- phase C: sequential per-batch scatter (set 1.0; last-write-wins rank) ----
__global__ void phaseC_kernel(const unsigned long long* __restrict__ key_obj,
                              float* __restrict__ ov_prior,
                              int* __restrict__ objinfo){
  int b = threadIdx.x;
  if (b >= Bn) return;
  int rank = -1;
  for (int o=0;o<On;o++){
    unsigned long long k = key_obj[(size_t)b*On+o];
    if ((unsigned)(k>>32) > 0u){            // iou > 0  <=> valid
      rank++;                               // jranks = cumsum(valid)-1
      int p = (int)(0xFFFFFFFFu - (unsigned)(k & 0xFFFFFFFFu));
      size_t bp = (size_t)b*Pn + p;
      ov_prior[bp] = 1.0f;
      objinfo[bp] = (objinfo[bp] & 256) | rank; // ascending o => overwrite == max(jr)
    }
  }
}

// ---- phase D: 4 priors/thread; per-WAVE shuffle reduce; no barriers, no atomics ----
__global__ void __launch_bounds__(256, 4)
phaseD_kernel(const float* __restrict__ odm_locs,
              const float* __restrict__ odm_scores,
              const float* __restrict__ boxes,
              const int* __restrict__ labels,
              const float* __restrict__ priors,
              const float* __restrict__ ov_prior,
              const int* __restrict__ objinfo,
              float* __restrict__ conf_neg,
              float* __restrict__ ploc,
              float* __restrict__ pconf,
              int* __restrict__ ppos){
  int b = blockIdx.y;
  int t = threadIdx.x;
  int p0 = (blockIdx.x*256 + t)*4;
  float locv = 0.0f, confpv = 0.0f; int posv = 0;
  if (p0 < Pn){                           // Pn%4==0 -> all 4 priors valid
    size_t bp0 = (size_t)b*Pn + p0;
    float4 sc4[11];
    const float4* src = (const float4*)(odm_scores + bp0*Cn);  // 16B-aligned
    #pragma unroll
    for (int i=0;i<11;i++) sc4[i] = src[i];
    int4   info4 = *(const int4*)(objinfo + bp0);
    float4 ovp4  = *(const float4*)(ov_prior + bp0);
    const float* sc = (const float*)sc4;   // constant indices only (post-unroll)
    float cn[4];
    #pragma unroll
    for (int j=0;j<4;j++){
      int info = (&info4.x)[j];
      int obj = info & 0xFF;
      bool ignored = (info & 256) != 0;
      int label = labels[b*On + obj];
      if ((&ovp4.x)[j] < THRESHOLD_F) label = 0;
      bool pos = label > 0;
      float m = sc[j*Cn];
      #pragma unroll
      for (int c=1;c<Cn;c++) m = fmaxf(m, sc[j*Cn+c]);
      float se = 0.0f, slab = 0.0f;
      #pragma unroll
      for (int c=0;c<Cn;c++){
        float v = sc[j*Cn+c];
        se += expf(v-m);
        if (c == label) slab = v;          // c is compile-time -> cndmask chain
      }
      float conf = logf(se) - (slab-m);
      cn[j] = (pos || ignored) ? 0.0f : conf;
      if (pos){
        posv += 1; confpv += conf;
        size_t bp = bp0 + j;
        float4 pc = ((const float4*)priors)[p0+j];
        float4 g  = ((const float4*)odm_locs)[bp];
        float cx = g.x*pc.z/10.0f + pc.x;
        float cy = g.y*pc.w/10.0f + pc.y;
        float w  = expf(g.z/5.0f)*pc.z;
        float h  = expf(g.w/5.0f)*pc.w;
        float dx1 = cx - w/2.0f, dy1 = cy - h/2.0f;
        float dx2 = cx + w/2.0f, dy2 = cy + h/2.0f;
        const float* gt = boxes + ((size_t)b*On + obj)*4;
        float gx1=gt[0], gy1=gt[1], gx2=gt[2], gy2=gt[3];
        float ltx=fmaxf(dx1,gx1), lty=fmaxf(dy1,gy1);
        float rbx=fminf(dx2,gx2), rby=fminf(dy2,gy2);
        float iw=fmaxf(rbx-ltx,0.0f), ih=fmaxf(rby-lty,0.0f);
        float inter=iw*ih;
        float ap=(dx2-dx1)*(dy2-dy1);
        float ag=(gx2-gx1)*(gy2-gy1);
        float iou = inter/((ap+ag)-inter);
        float cpx=(dx1+dx2)/2.0f, cpy=(dy1+dy2)/2.0f;
        float cgx=(gx1+gx2)/2.0f, cgy=(gy1+gy2)/2.0f;
        float ddx=cpx-cgx, ddy=cpy-cgy;
        float inter_diag = ddx*ddx + ddy*ddy;
        float cltx=fminf(dx1,gx1), clty=fminf(dy1,gy1);
        float crbx=fmaxf(dx2,gx2), crby=fmaxf(dy2,gy2);
        float odx=crbx-cltx, ody=crby-clty;
        float outer_diag = odx*odx + ody*ody;
        float diou = fminf(fmaxf(iou - inter_diag/outer_diag, -1.0f), 1.0f);
        locv += 1.0f - diou;
      }
    }
    *(float4*)(conf_neg + bp0) = make_float4(cn[0],cn[1],cn[2],cn[3]);
  }
  // per-wave butterfly reduction, lane 0 writes a unique slot -> zero contention
  #pragma unroll
  for (int d=32; d>0; d>>=1){
    locv   += __shfl_xor(locv,   d, 64);
    confpv += __shfl_xor(confpv, d, 64);
    posv   += __shfl_xor(posv,   d, 64);
  }
  if ((t & 63) == 0){
    int widx = b*WPB + (blockIdx.x<<2) + (t>>6);
    ploc[widx]  = locv;
    pconf[widx] = confpv;
    ppos[widx]  = posv;
  }
}

// ---- n_pos reduce ----
__global__ void npos_kernel(const int* __restrict__ ppos, int* __restrict__ n_pos){
  int b = threadIdx.x;
  if (b >= Bn) return;
  int s = 0;
  for (int w=0; w<WPB; w++) s += ppos[b*WPB + w];
  n_pos[b] = s;
}

// ---- phase E: 2-round radix select with per-bin (count,sum) ----
template<int ROUND>
__global__ void histE_kernel(const float* __restrict__ conf_neg,
                             const int* __restrict__ n_pos,
                             const unsigned* __restrict__ prefix,
                             const int* __restrict__ krem_st,
                             unsigned* __restrict__ gcnt,
                             float* __restrict__ gsum){
  int b = blockIdx.y, c = blockIdx.x, t = threadIdx.x;
  if (n_pos[b] <= 0) return;
  if (ROUND==1 && krem_st[b] < 0) return;   // K>=Pn handled in scan0
  __shared__ unsigned hc[4096];
  __shared__ float    hs[4096];
  for (int i=t;i<4096;i+=256){ hc[i]=0u; hs[i]=0.0f; }
  __syncthreads();
  unsigned pref = (ROUND==0)?0u:(prefix[b]>>20);
  const float* cn = conf_neg + (size_t)b*Pn;
  int p0 = c*CHUNK, p1 = min(Pn, p0+CHUNK);
  for (int p=p0+t; p<p1; p+=256){
    float v = cn[p];
    unsigned key = __float_as_uint(v);   // v >= 0 -> uint order == float order
    if (ROUND==0){
      unsigned d = key>>20;
      atomicAdd(&hc[d],1u); atomicAdd(&hs[d],v);
    } else {
      if ((key>>20)==pref){
        unsigned d = (key>>8)&0xFFFu;
        atomicAdd(&hc[d],1u); atomicAdd(&hs[d],v);
      }
    }
  }
  __syncthreads();
  unsigned* gc = gcnt + (size_t)b*4096;
  float*    gs = gsum + (size_t)b*4096;
  for (int i=t;i<4096;i+=256){
    if (hc[i]){ atomicAdd(&gc[i], hc[i]); atomicAdd(&gs[i], hs[i]); }
  }
}

template<int ROUND>
__global__ void scanE_kernel(const unsigned* __restrict__ gcnt,
                             const float* __restrict__ gsum,
                             const int* __restrict__ n_pos,
                             unsigned* __restrict__ prefix,
                             int* __restrict__ krem_st,
                             double* __restrict__ stop0,
                             double* __restrict__ phard){
  int b = blockIdx.x, t = threadIdx.x;
  int K = 2*n_pos[b];
  if (K <= 0){ if (ROUND==0 && t==0) phard[b] = 0.0; return; }
  if (ROUND==1 && krem_st[b] < 0) return;
  const unsigned* gc = gcnt + (size_t)b*4096;
  const float*    gs = gsum + (size_t)b*4096;
  unsigned cnt[16]; float sm[16];
  unsigned ts = 0;
  #pragma unroll
  for (int i=0;i<16;i++){ cnt[i]=gc[t*16+i]; sm[i]=gs[t*16+i]; ts+=cnt[i]; }
  __shared__ unsigned sh[256];
  __shared__ int s_sel;
  __shared__ double sd[256];
  if (t==0) s_sel = -1;
  sh[t]=ts;
  __syncthreads();
  for (int off=1; off<256; off<<=1){
    unsigned v = (t+off<256)? sh[t+off]:0u;   // read (after barrier)
    __syncthreads();
    sh[t]+=v;                                  // write
    __syncthreads();
  }
  if (ROUND==0 && K >= Pn){
    double ds=0.0;
    #pragma unroll
    for (int i=0;i<16;i++) ds += (double)sm[i];
    sd[t]=ds; __syncthreads();
    for (int st=128;st>0;st>>=1){ if(t<st) sd[t]+=sd[t+st]; __syncthreads(); }
    if (t==0){ phard[b]=sd[0]; krem_st[b]=-1; }
    return;
  }
  int krem = (ROUND==0)? K : krem_st[b];
  unsigned incl = sh[t];           // count of keys in bins >= this thread's lowest
  unsigned above = incl - ts;      // count in strictly-higher threads' bins
  if ((int)above < krem && krem <= (int)incl){
    int acc = (int)above;
    #pragma unroll
    for (int i=15;i>=0;i--){
      acc += (int)cnt[i];
      if (acc >= krem){
        unsigned sel = (unsigned)(t*16+i);
        int krem_new = krem - (acc - (int)cnt[i]);
        if (ROUND==0) prefix[b]  = sel<<20;
        else          prefix[b] |= sel<<8;
        krem_st[b] = krem_new;
        s_sel = (int)sel;
        break;
      }
    }
  }
  __syncthreads();
  int sel = s_sel;
  double ds = 0.0;
  #pragma unroll
  for (int i=0;i<16;i++){ int idx=t*16+i; if (idx > sel) ds += (double)sm[i]; }
  sd[t]=ds; __syncthreads();
  for (int st=128;st>0;st>>=1){ if(t<st) sd[t]+=sd[t+st]; __syncthreads(); }
  if (t==0){
    if (ROUND==0) stop0[b] = sd[0];
    else {
      // tie bucket approximated by its midpoint (error << absmax threshold)
      float vmid = __uint_as_float(prefix[b] | 0x80u);
      phard[b] = stop0[b] + sd[0] + (double)krem_st[b] * (double)vmid;
    }
  }
}

// ---- final combine: sum all partial arrays in doubles ----
__global__ void final_kernel(const int* __restrict__ n_pos,
                             const float* __restrict__ pseg,
                             const float* __restrict__ ploc,
                             const float* __restrict__ pconf,
                             const double* __restrict__ phard,
                             float* __restrict__ out){
  int t = threadIdx.x;
  double seg_s=0.0, loc_s=0.0, conf_s=0.0, hard_s=0.0;
  for (int i=t;i<SEGB;i+=256)     seg_s  += (double)pseg[i];
  for (int i=t;i<Bn*WPB;i+=256)   loc_s  += (double)ploc[i];
  for (int i=t;i<Bn*WPB;i+=256)   conf_s += (double)pconf[i];
  for (int i=t;i<Bn;i+=256)       hard_s += phard[i];
  int tp_s = (t < Bn) ? n_pos[t] : 0;
  __shared__ double sd[256];
  __shared__ int    si_[256];
  si_[t]=tp_s;
  sd[t]=seg_s;  __syncthreads();
  for (int st=128;st>0;st>>=1){ if(t<st){ sd[t]+=sd[t+st]; si_[t]+=si_[t+st]; } __syncthreads(); }
  double seg_t = sd[0]; int tp = si_[0];
  __syncthreads();
  sd[t]=loc_s;  __syncthreads();
  for (int st=128;st>0;st>>=1){ if(t<st) sd[t]+=sd[t+st]; __syncthreads(); }
  double loc_t = sd[0];
  __syncthreads();
  sd[t]=conf_s+hard_s; __syncthreads();
  for (int st=128;st>0;st>>=1){ if(t<st) sd[t]+=sd[t+st]; __syncthreads(); }
  double conf_t = sd[0];
  if (t==0){
    float total = (float)tp;
    float conf_loss = (float)conf_t / total;
    float loc_loss  = (float)loc_t / total;
    float seg_loss  = -(float)seg_t;
    out[0] = conf_loss + loc_loss + seg_loss;
  }
}

extern "C" void kernel_launch(void* const* d_in, const int* in_sizes, int n_in,
                              void* d_out, int out_size, void* d_ws, size_t ws_size,
                              hipStream_t stream) {
  const float* odm_locs   = (const float*)d_in[0];
  const float* odm_scores = (const float*)d_in[1];
  const float* att        = (const float*)d_in[2];
  const float* boxes      = (const float*)d_in[3];
  const int*   labels     = (const int*)d_in[4];
  const float* ign        = (const float*)d_in[5];
  const float* priors     = (const float*)d_in[6];
  float* out = (float*)d_out;

  size_t np = (size_t)Bn * Pn;
  float* ov_prior  = (float*)d_ws;                 // B*P f32
  int*   objinfo   = (int*)(ov_prior + np);        // B*P i32
  float* conf_neg  = (float*)(objinfo + np);       // B*P f32
  unsigned long long* key_obj = (unsigned long long*)(conf_neg + np); // B*O u64
  double* phard    = (double*)(key_obj + (size_t)Bn*On); // Bn f64
  int*    n_pos    = (int*)(phard + Bn);                 // B i32
  float*  pseg     = (float*)(n_pos + Bn);               // SEGB f32
  float*  ploc     = pseg + SEGB;                        // B*WPB f32
  float*  pconf    = ploc + (size_t)Bn*WPB;              // B*WPB f32
  int*    ppos     = (int*)(pconf + (size_t)Bn*WPB);     // B*WPB i32

  // radix-select scratch in the ov_prior region (dead after phaseD):
  unsigned* gcnt0 = (unsigned*)ov_prior;
  float*    gsum0 = (float*)(gcnt0 + (size_t)Bn*4096);
  unsigned* gcnt1 = (unsigned*)(gsum0 + (size_t)Bn*4096);
  float*    gsum1 = (float*)(gcnt1 + (size_t)Bn*4096);
  unsigned* prefix = (unsigned*)(gsum1 + (size_t)Bn*4096);
  int*      krem   = (int*)(prefix + Bn);
  double*   stop0  = (double*)(krem + Bn);   // 8B-aligned: 2MB+256B offset

  // only key_obj needs zeroing (atomicMax targets); partials fully written
  hipMemsetAsync(key_obj, 0, (size_t)Bn*On*8, stream);

  seg_kernel  <<<SEGB, 256, 0, stream>>>(att, pseg);
  phaseA_kernel<<<dim3(ABLK, Bn), 256, 0, stream>>>(boxes, ign, priors, ov_prior, objinfo);
  phaseB_kernel<<<dim3(PCn, On/OC, Bn), 256, 0, stream>>>(boxes, priors, key_obj);
  phaseC_kernel<<<1, 64, 0, stream>>>(key_obj, ov_prior, objinfo);
  phaseD_kernel<<<dim3(DBLK, Bn), 256, 0, stream>>>(odm_locs, odm_scores, boxes, labels,
                                                    priors, ov_prior, objinfo,
                                                    conf_neg, ploc, pconf, ppos);
  npos_kernel<<<1, 64, 0, stream>>>(ppos, n_pos);
  // ov_prior dead from here; reuse as radix scratch
  hipMemsetAsync(gcnt0, 0, 4*(size_t)Bn*4096*sizeof(unsigned), stream);
  histE_kernel<0><<<dim3(CHn, Bn), 256, 0, stream>>>(conf_neg, n_pos, prefix, krem, gcnt0, gsum0);
  scanE_kernel<0><<<Bn, 256, 0, stream>>>(gcnt0, gsum0, n_pos, prefix, krem, stop0, phard);
  histE_kernel<1><<<dim3(CHn, Bn), 256, 0, stream>>>(conf_neg, n_pos, prefix, krem, gcnt1, gsum1);
  scanE_kernel<1><<<Bn, 256, 0, stream>>>(gcnt1, gsum1, n_pos, prefix, krem, stop0, phard);
  final_kernel<<<1, 256, 0, stream>>>(n_pos, pseg, ploc, pconf, phard, out);
}

// Round 18
// 219.530 us; speedup vs baseline: 1.0366x; 1.0335x over previous
//
#include <hip/hip_runtime.h>
#include <math.h>

#define Bn 32
#define Pn 42840
#define On 64
#define NIn 8
#define Cn 11
#define ATT_N (32*56*96)
#define THRESHOLD_F 0.4f
#define THETA_F 0.1f
#define CHn 16
#define CHUNK ((Pn + CHn - 1)/CHn)
#define DBLK 42         /* phaseD blocks per batch */
#define WPB  (DBLK*4)   /* phaseD waves per batch = 168 */
#define SEGB ((ATT_N+255)/256)   /* 672 seg blocks */
#define FP 8            /* priors per thread in matchAB */
#define FBLK ((Pn + 256*FP - 1)/(256*FP))   /* 21 blocks per batch */

// opaque register pin: read-write empty asm -> compiler cannot rematerialize
#define PINF(x) asm volatile("" : "+v"(x))

// ---- seg loss: per-block partial (no atomics) ----
__global__ void seg_kernel(const float* __restrict__ att, float* __restrict__ pseg){
  int i = blockIdx.x*256 + threadIdx.x;
  float v = 0.0f;
  if (i < ATT_N) v = fmaxf(log1pf(-att[i]), -100.0f);
  __shared__ float s[256];
  int t = threadIdx.x;
  s[t]=v; __syncthreads();
  for (int st=128; st>0; st>>=1){ if (t<st) s[t]+=s[t+st]; __syncthreads(); }
  if (t==0) pseg[blockIdx.x] = s[0];
}

// ---- fused match: ONE pass over the O x P iou matrix reduces BOTH axes ----
// row (per-prior argmax over objects) -> ov_prior/objinfo
// col (per-object argmax over priors) -> key_obj via butterfly+LDS+global atomicMax
__global__ void __launch_bounds__(256, 4)
matchAB_kernel(const float* __restrict__ boxes,
               const float* __restrict__ ign,
               const float* __restrict__ priors,
               float* __restrict__ ov_prior,
               int* __restrict__ objinfo,
               unsigned long long* __restrict__ key_obj){
  __shared__ float sx1[On], sy1[On], sx2[On], sy2[On], sar[On];
  __shared__ float ix1[NIn], iy1[NIn], ix2[NIn], iy2[NIn], iar[NIn];
  __shared__ unsigned long long skey[On];
  int b = blockIdx.y, t = threadIdx.x;
  if (t < On){
    float4 v = ((const float4*)boxes)[b*On + t];
    sx1[t]=v.x; sy1[t]=v.y; sx2[t]=v.z; sy2[t]=v.w;
    sar[t]=(v.z-v.x)*(v.w-v.y);
    skey[t]=0ull;
  } else if (t < On+NIn){
    int o = t - On;
    float4 v = ((const float4*)ign)[b*NIn + o];
    ix1[o]=v.x; iy1[o]=v.y; ix2[o]=v.z; iy2[o]=v.w;
    iar[o]=(v.z-v.x)*(v.w-v.y);
  }
  __syncthreads();
  int p0 = (blockIdx.x*256 + t)*FP;
  bool active = (p0 < Pn);          // Pn%8==0 -> all 8 valid when active
  float px1[FP], py1[FP], px2[FP], py2[FP], pab[FP];
  #pragma unroll
  for (int q=0;q<FP;q++){
    float4 pc = active ? ((const float4*)priors)[p0+q]
                       : make_float4(0.f,0.f,0.f,0.f);
    px1[q]=pc.x - pc.z*0.5f; py1[q]=pc.y - pc.w*0.5f;
    px2[q]=pc.x + pc.z*0.5f; py2[q]=pc.y + pc.w*0.5f;
    pab[q]=(px2[q]-px1[q])*(py2[q]-py1[q]);
    PINF(px1[q]); PINF(py1[q]); PINF(px2[q]); PINF(py2[q]); PINF(pab[q]);
  }
  float best[FP]; int bo[FP];
  #pragma unroll
  for (int q=0;q<FP;q++){ best[q]=-1.0f; bo[q]=0; }
  #pragma unroll 1
  for (int o=0;o<On;o++){
    float ox1=sx1[o], oy1=sy1[o], ox2=sx2[o], oy2=sy2[o], oar=sar[o];
    float cmax=-1.0f; unsigned cp=0u;
    #pragma unroll
    for (int q=0;q<FP;q++){
      float ltx=fmaxf(ox1,px1[q]), lty=fmaxf(oy1,py1[q]);
      float rbx=fminf(ox2,px2[q]), rby=fminf(oy2,py2[q]);
      float w=fmaxf(rbx-ltx,0.0f), h=fmaxf(rby-lty,0.0f);
      float inter=w*h;
      float uni=(oar+pab[q])-inter;
      float iou = inter * __builtin_amdgcn_rcpf(uni);
      if (iou > best[q]){ best[q]=iou; bo[q]=o; }   // row argmax, first-occurrence
      if (iou > cmax){ cmax=iou; cp=(unsigned)(p0+q); } // col local, smallest p
    }
    unsigned long long key = active
      ? (((unsigned long long)__float_as_uint(cmax)<<32)
         | (unsigned long long)(0xFFFFFFFFu - cp))
      : 0ull;
    #pragma unroll
    for (int d=32; d>0; d>>=1){
      unsigned long long o2 = __shfl_xor(key, d, 64);
      if (o2 > key) key = o2;
    }
    if ((t & 63) == 0) atomicMax(&skey[o], key);
  }
  // ignored regions: per-prior max only
  float ib[FP];
  #pragma unroll
  for (int q=0;q<FP;q++) ib[q]=-1.0f;
  #pragma unroll
  for (int j=0;j<NIn;j++){
    float jx1=ix1[j], jy1=iy1[j], jx2=ix2[j], jy2=iy2[j], jar=iar[j];
    #pragma unroll
    for (int q=0;q<FP;q++){
      float ltx=fmaxf(jx1,px1[q]), lty=fmaxf(jy1,py1[q]);
      float rbx=fminf(jx2,px2[q]), rby=fminf(jy2,py2[q]);
      float w=fmaxf(rbx-ltx,0.0f), h=fmaxf(rby-lty,0.0f);
      float inter=w*h;
      float uni=(jar+pab[q])-inter;
      ib[q] = fmaxf(ib[q], inter * __builtin_amdgcn_rcpf(uni));
    }
  }
  if (active){
    size_t bp0 = (size_t)b*Pn + p0;
    int in_[FP];
    #pragma unroll
    for (int q=0;q<FP;q++)
      in_[q] = bo[q] | ((ib[q] >= THETA_F) ? 256 : 0);
    *(float4*)(ov_prior + bp0)     = make_float4(best[0],best[1],best[2],best[3]);
    *(float4*)(ov_prior + bp0 + 4) = make_float4(best[4],best[5],best[6],best[7]);
    *(int4*)(objinfo + bp0)        = make_int4(in_[0],in_[1],in_[2],in_[3]);
    *(int4*)(objinfo + bp0 + 4)    = make_int4(in_[4],in_[5],in_[6],in_[7]);
  }
  __syncthreads();
  if (t < On) atomicMax(&key_obj[(size_t)b*On + t], skey[t]);
}

// ---- phase C: sequential per-batch scatter (set 1.0; last-write-wins rank) ----
__global__ void phaseC_kernel(const unsigned long long* __restrict__ key_obj,
                              float* __restrict__ ov_prior,
                              int* __restrict__ objinfo){
  int b = threadIdx.x;
  if (b >= Bn) return;
  int rank = -1;
  for (int o=0;o<On;o++){
    unsigned long long k = key_obj[(size_t)b*On+o];
    if ((unsigned)(k>>32) > 0u){            // iou > 0  <=> valid
      rank++;                               // jranks = cumsum(valid)-1
      int p = (int)(0xFFFFFFFFu - (unsigned)(k & 0xFFFFFFFFu));
      size_t bp = (size_t)b*Pn + p;
      ov_prior[bp] = 1.0f;
      objinfo[bp] = (objinfo[bp] & 256) | rank; // ascending o => overwrite == max(jr)
    }
  }
}

// ---- phase D: 4 priors/thread; per-WAVE shuffle reduce; no barriers, no atomics ----
__global__ void __launch_bounds__(256, 4)
phaseD_kernel(const float* __restrict__ odm_locs,
              const float* __restrict__ odm_scores,
              const float* __restrict__ boxes,
              const int* __restrict__ labels,
              const float* __restrict__ priors,
              const float* __restrict__ ov_prior,
              const int* __restrict__ objinfo,
              float* __restrict__ conf_neg,
              float* __restrict__ ploc,
              float* __restrict__ pconf,
              int* __restrict__ ppos){
  int b = blockIdx.y;
  int t = threadIdx.x;
  int p0 = (blockIdx.x*256 + t)*4;
  float locv = 0.0f, confpv = 0.0f; int posv = 0;
  if (p0 < Pn){                           // Pn%4==0 -> all 4 priors valid
    size_t bp0 = (size_t)b*Pn + p0;
    float4 sc4[11];
    const float4* src = (const float4*)(odm_scores + bp0*Cn);  // 16B-aligned
    #pragma unroll
    for (int i=0;i<11;i++) sc4[i] = src[i];
    int4   info4 = *(const int4*)(objinfo + bp0);
    float4 ovp4  = *(const float4*)(ov_prior + bp0);
    const float* sc = (const float*)sc4;   // constant indices only (post-unroll)
    float cn[4];
    #pragma unroll
    for (int j=0;j<4;j++){
      int info = (&info4.x)[j];
      int obj = info & 0xFF;
      bool ignored = (info & 256) != 0;
      int label = labels[b*On + obj];
      if ((&ovp4.x)[j] < THRESHOLD_F) label = 0;
      bool pos = label > 0;
      float m = sc[j*Cn];
      #pragma unroll
      for (int c=1;c<Cn;c++) m = fmaxf(m, sc[j*Cn+c]);
      float se = 0.0f, slab = 0.0f;
      #pragma unroll
      for (int c=0;c<Cn;c++){
        float v = sc[j*Cn+c];
        se += expf(v-m);
        if (c == label) slab = v;          // c is compile-time -> cndmask chain
      }
      float conf = logf(se) - (slab-m);
      cn[j] = (pos || ignored) ? 0.0f : conf;
      if (pos){
        posv += 1; confpv += conf;
        size_t bp = bp0 + j;
        float4 pc = ((const float4*)priors)[p0+j];
        float4 g  = ((const float4*)odm_locs)[bp];
        float cx = g.x*pc.z/10.0f + pc.x;
        float cy = g.y*pc.w/10.0f + pc.y;
        float w  = expf(g.z/5.0f)*pc.z;
        float h  = expf(g.w/5.0f)*pc.w;
        float dx1 = cx - w/2.0f, dy1 = cy - h/2.0f;
        float dx2 = cx + w/2.0f, dy2 = cy + h/2.0f;
        const float* gt = boxes + ((size_t)b*On + obj)*4;
        float gx1=gt[0], gy1=gt[1], gx2=gt[2], gy2=gt[3];
        float ltx=fmaxf(dx1,gx1), lty=fmaxf(dy1,gy1);
        float rbx=fminf(dx2,gx2), rby=fminf(dy2,gy2);
        float iw=fmaxf(rbx-ltx,0.0f), ih=fmaxf(rby-lty,0.0f);
        float inter=iw*ih;
        float ap=(dx2-dx1)*(dy2-dy1);
        float ag=(gx2-gx1)*(gy2-gy1);
        float iou = inter/((ap+ag)-inter);
        float cpx=(dx1+dx2)/2.0f, cpy=(dy1+dy2)/2.0f;
        float cgx=(gx1+gx2)/2.0f, cgy=(gy1+gy2)/2.0f;
        float ddx=cpx-cgx, ddy=cpy-cgy;
        float inter_diag = ddx*ddx + ddy*ddy;
        float cltx=fminf(dx1,gx1), clty=fminf(dy1,gy1);
        float crbx=fmaxf(dx2,gx2), crby=fmaxf(dy2,gy2);
        float odx=crbx-cltx, ody=crby-clty;
        float outer_diag = odx*odx + ody*ody;
        float diou = fminf(fmaxf(iou - inter_diag/outer_diag, -1.0f), 1.0f);
        locv += 1.0f - diou;
      }
    }
    *(float4*)(conf_neg + bp0) = make_float4(cn[0],cn[1],cn[2],cn[3]);
  }
  // per-wave butterfly reduction, lane 0 writes a unique slot -> zero contention
  #pragma unroll
  for (int d=32; d>0; d>>=1){
    locv   += __shfl_xor(locv,   d, 64);
    confpv += __shfl_xor(confpv, d, 64);
    posv   += __shfl_xor(posv,   d, 64);
  }
  if ((t & 63) == 0){
    int widx = b*WPB + (blockIdx.x<<2) + (t>>6);
    ploc[widx]  = locv;
    pconf[widx] = confpv;
    ppos[widx]  = posv;
  }
}

// ---- n_pos reduce ----
__global__ void npos_kernel(const int* __restrict__ ppos, int* __restrict__ n_pos){
  int b = threadIdx.x;
  if (b >= Bn) return;
  int s = 0;
  for (int w=0; w<WPB; w++) s += ppos[b*WPB + w];
  n_pos[b] = s;
}

// ---- phase E: 2-round radix select with per-bin (count,sum) ----
template<int ROUND>
__global__ void histE_kernel(const float* __restrict__ conf_neg,
                             const int* __restrict__ n_pos,
                             const unsigned* __restrict__ prefix,
                             const int* __restrict__ krem_st,
                             unsigned* __restrict__ gcnt,
                             float* __restrict__ gsum){
  int b = blockIdx.y, c = blockIdx.x, t = threadIdx.x;
  if (n_pos[b] <= 0) return;
  if (ROUND==1 && krem_st[b] < 0) return;   // K>=Pn handled in scan0
  __shared__ unsigned hc[4096];
  __shared__ float    hs[4096];
  for (int i=t;i<4096;i+=256){ hc[i]=0u; hs[i]=0.0f; }
  __syncthreads();
  unsigned pref = (ROUND==0)?0u:(prefix[b]>>20);
  const float* cn = conf_neg + (size_t)b*Pn;
  int p0 = c*CHUNK, p1 = min(Pn, p0+CHUNK);
  for (int p=p0+t; p<p1; p+=256){
    float v = cn[p];
    unsigned key = __float_as_uint(v);   // v >= 0 -> uint order == float order
    if (ROUND==0){
      unsigned d = key>>20;
      atomicAdd(&hc[d],1u); atomicAdd(&hs[d],v);
    } else {
      if ((key>>20)==pref){
        unsigned d = (key>>8)&0xFFFu;
        atomicAdd(&hc[d],1u); atomicAdd(&hs[d],v);
      }
    }
  }
  __syncthreads();
  unsigned* gc = gcnt + (size_t)b*4096;
  float*    gs = gsum + (size_t)b*4096;
  for (int i=t;i<4096;i+=256){
    if (hc[i]){ atomicAdd(&gc[i], hc[i]); atomicAdd(&gs[i], hs[i]); }
  }
}

template<int ROUND>
__global__ void scanE_kernel(const unsigned* __restrict__ gcnt,
                             const float* __restrict__ gsum,
                             const int* __restrict__ n_pos,
                             unsigned* __restrict__ prefix,
                             int* __restrict__ krem_st,
                             double* __restrict__ stop0,
                             double* __restrict__ phard){
  int b = blockIdx.x, t = threadIdx.x;
  int K = 2*n_pos[b];
  if (K <= 0){ if (ROUND==0 && t==0) phard[b] = 0.0; return; }
  if (ROUND==1 && krem_st[b] < 0) return;
  const unsigned* gc = gcnt + (size_t)b*4096;
  const float*    gs = gsum + (size_t)b*4096;
  unsigned cnt[16]; float sm[16];
  unsigned ts = 0;
  #pragma unroll
  for (int i=0;i<16;i++){ cnt[i]=gc[t*16+i]; sm[i]=gs[t*16+i]; ts+=cnt[i]; }
  __shared__ unsigned sh[256];
  __shared__ int s_sel;
  __shared__ double sd[256];
  if (t==0) s_sel = -1;
  sh[t]=ts;
  __syncthreads();
  for (int off=1; off<256; off<<=1){
    unsigned v = (t+off<256)? sh[t+off]:0u;   // read (after barrier)
    __syncthreads();
    sh[t]+=v;                                  // write
    __syncthreads();
  }
  if (ROUND==0 && K >= Pn){
    double ds=0.0;
    #pragma unroll
    for (int i=0;i<16;i++) ds += (double)sm[i];
    sd[t]=ds; __syncthreads();
    for (int st=128;st>0;st>>=1){ if(t<st) sd[t]+=sd[t+st]; __syncthreads(); }
    if (t==0){ phard[b]=sd[0]; krem_st[b]=-1; }
    return;
  }
  int krem = (ROUND==0)? K : krem_st[b];
  unsigned incl = sh[t];           // count of keys in bins >= this thread's lowest
  unsigned above = incl - ts;      // count in strictly-higher threads' bins
  if ((int)above < krem && krem <= (int)incl){
    int acc = (int)above;
    #pragma unroll
    for (int i=15;i>=0;i--){
      acc += (int)cnt[i];
      if (acc >= krem){
        unsigned sel = (unsigned)(t*16+i);
        int krem_new = krem - (acc - (int)cnt[i]);
        if (ROUND==0) prefix[b]  = sel<<20;
        else          prefix[b] |= sel<<8;
        krem_st[b] = krem_new;
        s_sel = (int)sel;
        break;
      }
    }
  }
  __syncthreads();
  int sel = s_sel;
  double ds = 0.0;
  #pragma unroll
  for (int i=0;i<16;i++){ int idx=t*16+i; if (idx > sel) ds += (double)sm[i]; }
  sd[t]=ds; __syncthreads();
  for (int st=128;st>0;st>>=1){ if(t<st) sd[t]+=sd[t+st]; __syncthreads(); }
  if (t==0){
    if (ROUND==0) stop0[b] = sd[0];
    else {
      // tie bucket approximated by its midpoint (error << absmax threshold)
      float vmid = __uint_as_float(prefix[b] | 0x80u);
      phard[b] = stop0[b] + sd[0] + (double)krem_st[b] * (double)vmid;
    }
  }
}

// ---- final combine: sum all partial arrays in doubles ----
__global__ void final_kernel(const int* __restrict__ n_pos,
                             const float* __restrict__ pseg,
                             const float* __restrict__ ploc,
                             const float* __restrict__ pconf,
                             const double* __restrict__ phard,
                             float* __restrict__ out){
  int t = threadIdx.x;
  double seg_s=0.0, loc_s=0.0, conf_s=0.0, hard_s=0.0;
  for (int i=t;i<SEGB;i+=256)     seg_s  += (double)pseg[i];
  for (int i=t;i<Bn*WPB;i+=256)   loc_s  += (double)ploc[i];
  for (int i=t;i<Bn*WPB;i+=256)   conf_s += (double)pconf[i];
  for (int i=t;i<Bn;i+=256)       hard_s += phard[i];
  int tp_s = (t < Bn) ? n_pos[t] : 0;
  __shared__ double sd[256];
  __shared__ int    si_[256];
  si_[t]=tp_s;
  sd[t]=seg_s;  __syncthreads();
  for (int st=128;st>0;st>>=1){ if(t<st){ sd[t]+=sd[t+st]; si_[t]+=si_[t+st]; } __syncthreads(); }
  double seg_t = sd[0]; int tp = si_[0];
  __syncthreads();
  sd[t]=loc_s;  __syncthreads();
  for (int st=128;st>0;st>>=1){ if(t<st) sd[t]+=sd[t+st]; __syncthreads(); }
  double loc_t = sd[0];
  __syncthreads();
  sd[t]=conf_s+hard_s; __syncthreads();
  for (int st=128;st>0;st>>=1){ if(t<st) sd[t]+=sd[t+st]; __syncthreads(); }
  double conf_t = sd[0];
  if (t==0){
    float total = (float)tp;
    float conf_loss = (float)conf_t / total;
    float loc_loss  = (float)loc_t / total;
    float seg_loss  = -(float)seg_t;
    out[0] = conf_loss + loc_loss + seg_loss;
  }
}

extern "C" void kernel_launch(void* const* d_in, const int* in_sizes, int n_in,
                              void* d_out, int out_size, void* d_ws, size_t ws_size,
                              hipStream_t stream) {
  const float* odm_locs   = (const float*)d_in[0];
  const float* odm_scores = (const float*)d_in[1];
  const float* att        = (const float*)d_in[2];
  const float* boxes      = (const float*)d_in[3];
  const int*   labels     = (const int*)d_in[4];
  const float* ign        = (const float*)d_in[5];
  const float* priors     = (const float*)d_in[6];
  float* out = (float*)d_out;

  size_t np = (size_t)Bn * Pn;
  float* ov_prior  = (float*)d_ws;                 // B*P f32
  int*   objinfo   = (int*)(ov_prior + np);        // B*P i32
  float* conf_neg  = (float*)(objinfo + np);       // B*P f32
  unsigned long long* key_obj = (unsigned long long*)(conf_neg + np); // B*O u64
  double* phard    = (double*)(key_obj + (size_t)Bn*On); // Bn f64
  int*    n_pos    = (int*)(phard + Bn);                 // B i32
  float*  pseg     = (float*)(n_pos + Bn);               // SEGB f32
  float*  ploc     = pseg + SEGB;                        // B*WPB f32
  float*  pconf    = ploc + (size_t)Bn*WPB;              // B*WPB f32
  int*    ppos     = (int*)(pconf + (size_t)Bn*WPB);     // B*WPB i32

  // radix-select scratch in the ov_prior region (dead after phaseD):
  unsigned* gcnt0 = (unsigned*)ov_prior;
  float*    gsum0 = (float*)(gcnt0 + (size_t)Bn*4096);
  unsigned* gcnt1 = (unsigned*)(gsum0 + (size_t)Bn*4096);
  float*    gsum1 = (float*)(gcnt1 + (size_t)Bn*4096);
  unsigned* prefix = (unsigned*)(gsum1 + (size_t)Bn*4096);
  int*      krem   = (int*)(prefix + Bn);
  double*   stop0  = (double*)(krem + Bn);   // 8B-aligned

  // only key_obj needs zeroing (atomicMax targets); partials fully written
  hipMemsetAsync(key_obj, 0, (size_t)Bn*On*8, stream);

  seg_kernel   <<<SEGB, 256, 0, stream>>>(att, pseg);
  matchAB_kernel<<<dim3(FBLK, Bn), 256, 0, stream>>>(boxes, ign, priors,
                                                     ov_prior, objinfo, key_obj);
  phaseC_kernel<<<1, 64, 0, stream>>>(key_obj, ov_prior, objinfo);
  phaseD_kernel<<<dim3(DBLK, Bn), 256, 0, stream>>>(odm_locs, odm_scores, boxes, labels,
                                                    priors, ov_prior, objinfo,
                                                    conf_neg, ploc, pconf, ppos);
  npos_kernel<<<1, 64, 0, stream>>>(ppos, n_pos);
  // ov_prior dead from here; reuse as radix scratch
  hipMemsetAsync(gcnt0, 0, 4*(size_t)Bn*4096*sizeof(unsigned), stream);
  histE_kernel<0><<<dim3(CHn, Bn), 256, 0, stream>>>(conf_neg, n_pos, prefix, krem, gcnt0, gsum0);
  scanE_kernel<0><<<Bn, 256, 0, stream>>>(gcnt0, gsum0, n_pos, prefix, krem, stop0, phard);
  histE_kernel<1><<<dim3(CHn, Bn), 256, 0, stream>>>(conf_neg, n_pos, prefix, krem, gcnt1, gsum1);
  scanE_kernel<1><<<Bn, 256, 0, stream>>>(gcnt1, gsum1, n_pos, prefix, krem, stop0, phard);
  final_kernel<<<1, 256, 0, stream>>>(n_pos, pseg, ploc, pconf, phard, out);
}

// Round 19
// 212.329 us; speedup vs baseline: 1.0717x; 1.0339x over previous
//
#include <hip/hip_runtime.h>
#include <math.h>

#define Bn 32
#define Pn 42840
#define On 64
#define NIn 8
#define Cn 11
#define ATT_N (32*56*96)
#define THRESHOLD_F 0.4f
#define THETA_F 0.1f
#define CHn 16
#define CHUNK ((Pn + CHn - 1)/CHn)
#define DBLK 42         /* phaseD blocks per batch */
#define WPB  (DBLK*4)   /* phaseD waves per batch = 168 */
#define SEGB ((ATT_N+255)/256)   /* 672 seg blocks */
#define FP 4            /* priors per thread in matchAB */
#define FBLK ((Pn + 256*FP - 1)/(256*FP))   /* 42 blocks per batch */

// opaque register pin: read-write empty asm -> compiler cannot rematerialize
#define PINF(x) asm volatile("" : "+v"(x))

// ---- seg loss: per-block partial (no atomics) ----
__global__ void seg_kernel(const float* __restrict__ att, float* __restrict__ pseg){
  int i = blockIdx.x*256 + threadIdx.x;
  float v = 0.0f;
  if (i < ATT_N) v = fmaxf(log1pf(-att[i]), -100.0f);
  __shared__ float s[256];
  int t = threadIdx.x;
  s[t]=v; __syncthreads();
  for (int st=128; st>0; st>>=1){ if (t<st) s[t]+=s[t+st]; __syncthreads(); }
  if (t==0) pseg[blockIdx.x] = s[0];
}

// ---- fused match: ONE pass over the O x P iou matrix reduces BOTH axes ----
__global__ void __launch_bounds__(256, 4)
matchAB_kernel(const float* __restrict__ boxes,
               const float* __restrict__ ign,
               const float* __restrict__ priors,
               float* __restrict__ ov_prior,
               int* __restrict__ objinfo,
               unsigned long long* __restrict__ key_obj){
  __shared__ float sx1[On], sy1[On], sx2[On], sy2[On], sar[On];
  __shared__ float ix1[NIn], iy1[NIn], ix2[NIn], iy2[NIn], iar[NIn];
  __shared__ unsigned long long skey[On];
  int b = blockIdx.y, t = threadIdx.x;
  if (t < On){
    float4 v = ((const float4*)boxes)[b*On + t];
    sx1[t]=v.x; sy1[t]=v.y; sx2[t]=v.z; sy2[t]=v.w;
    sar[t]=(v.z-v.x)*(v.w-v.y);
    skey[t]=0ull;
  } else if (t < On+NIn){
    int o = t - On;
    float4 v = ((const float4*)ign)[b*NIn + o];
    ix1[o]=v.x; iy1[o]=v.y; ix2[o]=v.z; iy2[o]=v.w;
    iar[o]=(v.z-v.x)*(v.w-v.y);
  }
  __syncthreads();
  int p0 = (blockIdx.x*256 + t)*FP;
  bool active = (p0 < Pn);          // Pn%4==0 -> all 4 valid when active
  float px1[FP], py1[FP], px2[FP], py2[FP], pab[FP];
  #pragma unroll
  for (int q=0;q<FP;q++){
    float4 pc = active ? ((const float4*)priors)[p0+q]
                       : make_float4(0.f,0.f,0.f,0.f);
    px1[q]=pc.x - pc.z*0.5f; py1[q]=pc.y - pc.w*0.5f;
    px2[q]=pc.x + pc.z*0.5f; py2[q]=pc.y + pc.w*0.5f;
    pab[q]=(px2[q]-px1[q])*(py2[q]-py1[q]);
    PINF(px1[q]); PINF(py1[q]); PINF(px2[q]); PINF(py2[q]); PINF(pab[q]);
  }
  float best[FP]; int bo[FP];
  #pragma unroll
  for (int q=0;q<FP;q++){ best[q]=-1.0f; bo[q]=0; }
  #pragma unroll 1
  for (int o=0;o<On;o++){
    float ox1=sx1[o], oy1=sy1[o], ox2=sx2[o], oy2=sy2[o], oar=sar[o];
    float cmax=-1.0f; unsigned cp=0u;
    #pragma unroll
    for (int q=0;q<FP;q++){
      float ltx=fmaxf(ox1,px1[q]), lty=fmaxf(oy1,py1[q]);
      float rbx=fminf(ox2,px2[q]), rby=fminf(oy2,py2[q]);
      float w=fmaxf(rbx-ltx,0.0f), h=fmaxf(rby-lty,0.0f);
      float inter=w*h;
      float uni=(oar+pab[q])-inter;
      float iou = inter * __builtin_amdgcn_rcpf(uni);
      if (iou > best[q]){ best[q]=iou; bo[q]=o; }   // row argmax, first-occurrence
      if (iou > cmax){ cmax=iou; cp=(unsigned)(p0+q); } // col local, smallest p
    }
    unsigned long long key = active
      ? (((unsigned long long)__float_as_uint(cmax)<<32)
         | (unsigned long long)(0xFFFFFFFFu - cp))
      : 0ull;
    #pragma unroll
    for (int d=32; d>0; d>>=1){
      unsigned long long o2 = __shfl_xor(key, d, 64);
      if (o2 > key) key = o2;
    }
    if ((t & 63) == 0) atomicMax(&skey[o], key);
  }
  // ignored regions: per-prior max only
  float ib[FP];
  #pragma unroll
  for (int q=0;q<FP;q++) ib[q]=-1.0f;
  #pragma unroll
  for (int j=0;j<NIn;j++){
    float jx1=ix1[j], jy1=iy1[j], jx2=ix2[j], jy2=iy2[j], jar=iar[j];
    #pragma unroll
    for (int q=0;q<FP;q++){
      float ltx=fmaxf(jx1,px1[q]), lty=fmaxf(jy1,py1[q]);
      float rbx=fminf(jx2,px2[q]), rby=fminf(jy2,py2[q]);
      float w=fmaxf(rbx-ltx,0.0f), h=fmaxf(rby-lty,0.0f);
      float inter=w*h;
      float uni=(jar+pab[q])-inter;
      ib[q] = fmaxf(ib[q], inter * __builtin_amdgcn_rcpf(uni));
    }
  }
  if (active){
    size_t bp0 = (size_t)b*Pn + p0;
    int in_[FP];
    #pragma unroll
    for (int q=0;q<FP;q++)
      in_[q] = bo[q] | ((ib[q] >= THETA_F) ? 256 : 0);
    *(float4*)(ov_prior + bp0) = make_float4(best[0],best[1],best[2],best[3]);
    *(int4*)(objinfo + bp0)    = make_int4(in_[0],in_[1],in_[2],in_[3]);
  }
  __syncthreads();
  if (t < On) atomicMax(&key_obj[(size_t)b*On + t], skey[t]);
}

// ---- phase C: sequential per-batch scatter (set 1.0; last-write-wins rank) ----
__global__ void phaseC_kernel(const unsigned long long* __restrict__ key_obj,
                              float* __restrict__ ov_prior,
                              int* __restrict__ objinfo){
  int b = threadIdx.x;
  if (b >= Bn) return;
  int rank = -1;
  for (int o=0;o<On;o++){
    unsigned long long k = key_obj[(size_t)b*On+o];
    if ((unsigned)(k>>32) > 0u){            // iou > 0  <=> valid
      rank++;                               // jranks = cumsum(valid)-1
      int p = (int)(0xFFFFFFFFu - (unsigned)(k & 0xFFFFFFFFu));
      size_t bp = (size_t)b*Pn + p;
      ov_prior[bp] = 1.0f;
      objinfo[bp] = (objinfo[bp] & 256) | rank; // ascending o => overwrite == max(jr)
    }
  }
}

// ---- phase D: 4 priors/thread; per-WAVE shuffle reduce; no barriers, no atomics ----
__global__ void __launch_bounds__(256, 4)
phaseD_kernel(const float* __restrict__ odm_locs,
              const float* __restrict__ odm_scores,
              const float* __restrict__ boxes,
              const int* __restrict__ labels,
              const float* __restrict__ priors,
              const float* __restrict__ ov_prior,
              const int* __restrict__ objinfo,
              float* __restrict__ conf_neg,
              float* __restrict__ ploc,
              float* __restrict__ pconf,
              int* __restrict__ ppos){
  int b = blockIdx.y;
  int t = threadIdx.x;
  int p0 = (blockIdx.x*256 + t)*4;
  float locv = 0.0f, confpv = 0.0f; int posv = 0;
  if (p0 < Pn){                           // Pn%4==0 -> all 4 priors valid
    size_t bp0 = (size_t)b*Pn + p0;
    float4 sc4[11];
    const float4* src = (const float4*)(odm_scores + bp0*Cn);  // 16B-aligned
    #pragma unroll
    for (int i=0;i<11;i++) sc4[i] = src[i];
    int4   info4 = *(const int4*)(objinfo + bp0);
    float4 ovp4  = *(const float4*)(ov_prior + bp0);
    const float* sc = (const float*)sc4;   // constant indices only (post-unroll)
    float cn[4];
    #pragma unroll
    for (int j=0;j<4;j++){
      int info = (&info4.x)[j];
      int obj = info & 0xFF;
      bool ignored = (info & 256) != 0;
      int label = labels[b*On + obj];
      if ((&ovp4.x)[j] < THRESHOLD_F) label = 0;
      bool pos = label > 0;
      float m = sc[j*Cn];
      #pragma unroll
      for (int c=1;c<Cn;c++) m = fmaxf(m, sc[j*Cn+c]);
      float se = 0.0f, slab = 0.0f;
      #pragma unroll
      for (int c=0;c<Cn;c++){
        float v = sc[j*Cn+c];
        se += expf(v-m);
        if (c == label) slab = v;          // c is compile-time -> cndmask chain
      }
      float conf = logf(se) - (slab-m);
      cn[j] = (pos || ignored) ? 0.0f : conf;
      if (pos){
        posv += 1; confpv += conf;
        size_t bp = bp0 + j;
        float4 pc = ((const float4*)priors)[p0+j];
        float4 g  = ((const float4*)odm_locs)[bp];
        float cx = g.x*pc.z/10.0f + pc.x;
        float cy = g.y*pc.w/10.0f + pc.y;
        float w  = expf(g.z/5.0f)*pc.z;
        float h  = expf(g.w/5.0f)*pc.w;
        float dx1 = cx - w/2.0f, dy1 = cy - h/2.0f;
        float dx2 = cx + w/2.0f, dy2 = cy + h/2.0f;
        const float* gt = boxes + ((size_t)b*On + obj)*4;
        float gx1=gt[0], gy1=gt[1], gx2=gt[2], gy2=gt[3];
        float ltx=fmaxf(dx1,gx1), lty=fmaxf(dy1,gy1);
        float rbx=fminf(dx2,gx2), rby=fminf(dy2,gy2);
        float iw=fmaxf(rbx-ltx,0.0f), ih=fmaxf(rby-lty,0.0f);
        float inter=iw*ih;
        float ap=(dx2-dx1)*(dy2-dy1);
        float ag=(gx2-gx1)*(gy2-gy1);
        float iou = inter/((ap+ag)-inter);
        float cpx=(dx1+dx2)/2.0f, cpy=(dy1+dy2)/2.0f;
        float cgx=(gx1+gx2)/2.0f, cgy=(gy1+gy2)/2.0f;
        float ddx=cpx-cgx, ddy=cpy-cgy;
        float inter_diag = ddx*ddx + ddy*ddy;
        float cltx=fminf(dx1,gx1), clty=fminf(dy1,gy1);
        float crbx=fmaxf(dx2,gx2), crby=fmaxf(dy2,gy2);
        float odx=crbx-cltx, ody=crby-clty;
        float outer_diag = odx*odx + ody*ody;
        float diou = fminf(fmaxf(iou - inter_diag/outer_diag, -1.0f), 1.0f);
        locv += 1.0f - diou;
      }
    }
    *(float4*)(conf_neg + bp0) = make_float4(cn[0],cn[1],cn[2],cn[3]);
  }
  // per-wave butterfly reduction, lane 0 writes a unique slot -> zero contention
  #pragma unroll
  for (int d=32; d>0; d>>=1){
    locv   += __shfl_xor(locv,   d, 64);
    confpv += __shfl_xor(confpv, d, 64);
    posv   += __shfl_xor(posv,   d, 64);
  }
  if ((t & 63) == 0){
    int widx = b*WPB + (blockIdx.x<<2) + (t>>6);
    ploc[widx]  = locv;
    pconf[widx] = confpv;
    ppos[widx]  = posv;
  }
}

// ---- n_pos reduce ----
__global__ void npos_kernel(const int* __restrict__ ppos, int* __restrict__ n_pos){
  int b = threadIdx.x;
  if (b >= Bn) return;
  int s = 0;
  for (int w=0; w<WPB; w++) s += ppos[b*WPB + w];
  n_pos[b] = s;
}

// ---- phase E: 2-round radix select with per-bin (count,sum) ----
template<int ROUND>
__global__ void histE_kernel(const float* __restrict__ conf_neg,
                             const int* __restrict__ n_pos,
                             const unsigned* __restrict__ prefix,
                             const int* __restrict__ krem_st,
                             unsigned* __restrict__ gcnt,
                             float* __restrict__ gsum){
  int b = blockIdx.y, c = blockIdx.x, t = threadIdx.x;
  if (n_pos[b] <= 0) return;
  if (ROUND==1 && krem_st[b] < 0) return;   // K>=Pn handled in scan0
  __shared__ unsigned hc[4096];
  __shared__ float    hs[4096];
  for (int i=t;i<4096;i+=256){ hc[i]=0u; hs[i]=0.0f; }
  __syncthreads();
  unsigned pref = (ROUND==0)?0u:(prefix[b]>>20);
  const float* cn = conf_neg + (size_t)b*Pn;
  int p0 = c*CHUNK, p1 = min(Pn, p0+CHUNK);
  for (int p=p0+t; p<p1; p+=256){
    float v = cn[p];
    unsigned key = __float_as_uint(v);   // v >= 0 -> uint order == float order
    if (ROUND==0){
      unsigned d = key>>20;
      atomicAdd(&hc[d],1u); atomicAdd(&hs[d],v);
    } else {
      if ((key>>20)==pref){
        unsigned d = (key>>8)&0xFFFu;
        atomicAdd(&hc[d],1u); atomicAdd(&hs[d],v);
      }
    }
  }
  __syncthreads();
  unsigned* gc = gcnt + (size_t)b*4096;
  float*    gs = gsum + (size_t)b*4096;
  for (int i=t;i<4096;i+=256){
    if (hc[i]){ atomicAdd(&gc[i], hc[i]); atomicAdd(&gs[i], hs[i]); }
  }
}

template<int ROUND>
__global__ void scanE_kernel(const unsigned* __restrict__ gcnt,
                             const float* __restrict__ gsum,
                             const int* __restrict__ n_pos,
                             unsigned* __restrict__ prefix,
                             int* __restrict__ krem_st,
                             double* __restrict__ stop0,
                             double* __restrict__ phard){
  int b = blockIdx.x, t = threadIdx.x;
  int K = 2*n_pos[b];
  if (K <= 0){ if (ROUND==0 && t==0) phard[b] = 0.0; return; }
  if (ROUND==1 && krem_st[b] < 0) return;
  const unsigned* gc = gcnt + (size_t)b*4096;
  const float*    gs = gsum + (size_t)b*4096;
  unsigned cnt[16]; float sm[16];
  unsigned ts = 0;
  #pragma unroll
  for (int i=0;i<16;i++){ cnt[i]=gc[t*16+i]; sm[i]=gs[t*16+i]; ts+=cnt[i]; }
  __shared__ unsigned sh[256];
  __shared__ int s_sel;
  __shared__ double sd[256];
  if (t==0) s_sel = -1;
  sh[t]=ts;
  __syncthreads();
  for (int off=1; off<256; off<<=1){
    unsigned v = (t+off<256)? sh[t+off]:0u;   // read (after barrier)
    __syncthreads();
    sh[t]+=v;                                  // write
    __syncthreads();
  }
  if (ROUND==0 && K >= Pn){
    double ds=0.0;
    #pragma unroll
    for (int i=0;i<16;i++) ds += (double)sm[i];
    sd[t]=ds; __syncthreads();
    for (int st=128;st>0;st>>=1){ if(t<st) sd[t]+=sd[t+st]; __syncthreads(); }
    if (t==0){ phard[b]=sd[0]; krem_st[b]=-1; }
    return;
  }
  int krem = (ROUND==0)? K : krem_st[b];
  unsigned incl = sh[t];           // count of keys in bins >= this thread's lowest
  unsigned above = incl - ts;      // count in strictly-higher threads' bins
  if ((int)above < krem && krem <= (int)incl){
    int acc = (int)above;
    #pragma unroll
    for (int i=15;i>=0;i--){
      acc += (int)cnt[i];
      if (acc >= krem){
        unsigned sel = (unsigned)(t*16+i);
        int krem_new = krem - (acc - (int)cnt[i]);
        if (ROUND==0) prefix[b]  = sel<<20;
        else          prefix[b] |= sel<<8;
        krem_st[b] = krem_new;
        s_sel = (int)sel;
        break;
      }
    }
  }
  __syncthreads();
  int sel = s_sel;
  double ds = 0.0;
  #pragma unroll
  for (int i=0;i<16;i++){ int idx=t*16+i; if (idx > sel) ds += (double)sm[i]; }
  sd[t]=ds; __syncthreads();
  for (int st=128;st>0;st>>=1){ if(t<st) sd[t]+=sd[t+st]; __syncthreads(); }
  if (t==0){
    if (ROUND==0) stop0[b] = sd[0];
    else {
      // tie bucket approximated by its midpoint (error << absmax threshold)
      float vmid = __uint_as_float(prefix[b] | 0x80u);
      phard[b] = stop0[b] + sd[0] + (double)krem_st[b] * (double)vmid;
    }
  }
}

// ---- final combine: sum all partial arrays in doubles ----
__global__ void final_kernel(const int* __restrict__ n_pos,
                             const float* __restrict__ pseg,
                             const float* __restrict__ ploc,
                             const float* __restrict__ pconf,
                             const double* __restrict__ phard,
                             float* __restrict__ out){
  int t = threadIdx.x;
  double seg_s=0.0, loc_s=0.0, conf_s=0.0, hard_s=0.0;
  for (int i=t;i<SEGB;i+=256)     seg_s  += (double)pseg[i];
  for (int i=t;i<Bn*WPB;i+=256)   loc_s  += (double)ploc[i];
  for (int i=t;i<Bn*WPB;i+=256)   conf_s += (double)pconf[i];
  for (int i=t;i<Bn;i+=256)       hard_s += phard[i];
  int tp_s = (t < Bn) ? n_pos[t] : 0;
  __shared__ double sd[256];
  __shared__ int    si_[256];
  si_[t]=tp_s;
  sd[t]=seg_s;  __syncthreads();
  for (int st=128;st>0;st>>=1){ if(t<st){ sd[t]+=sd[t+st]; si_[t]+=si_[t+st]; } __syncthreads(); }
  double seg_t = sd[0]; int tp = si_[0];
  __syncthreads();
  sd[t]=loc_s;  __syncthreads();
  for (int st=128;st>0;st>>=1){ if(t<st) sd[t]+=sd[t+st]; __syncthreads(); }
  double loc_t = sd[0];
  __syncthreads();
  sd[t]=conf_s+hard_s; __syncthreads();
  for (int st=128;st>0;st>>=1){ if(t<st) sd[t]+=sd[t+st]; __syncthreads(); }
  double conf_t = sd[0];
  if (t==0){
    float total = (float)tp;
    float conf_loss = (float)conf_t / total;
    float loc_loss  = (float)loc_t / total;
    float seg_loss  = -(float)seg_t;
    out[0] = conf_loss + loc_loss + seg_loss;
  }
}

extern "C" void kernel_launch(void* const* d_in, const int* in_sizes, int n_in,
                              void* d_out, int out_size, void* d_ws, size_t ws_size,
                              hipStream_t stream) {
  const float* odm_locs   = (const float*)d_in[0];
  const float* odm_scores = (const float*)d_in[1];
  const float* att        = (const float*)d_in[2];
  const float* boxes      = (const float*)d_in[3];
  const int*   labels     = (const int*)d_in[4];
  const float* ign        = (const float*)d_in[5];
  const float* priors     = (const float*)d_in[6];
  float* out = (float*)d_out;

  size_t np = (size_t)Bn * Pn;
  float* ov_prior  = (float*)d_ws;                 // B*P f32
  int*   objinfo   = (int*)(ov_prior + np);        // B*P i32
  float* conf_neg  = (float*)(objinfo + np);       // B*P f32
  unsigned long long* key_obj = (unsigned long long*)(conf_neg + np); // B*O u64
  double* phard    = (double*)(key_obj + (size_t)Bn*On); // Bn f64
  int*    n_pos    = (int*)(phard + Bn);                 // B i32
  float*  pseg     = (float*)(n_pos + Bn);               // SEGB f32
  float*  ploc     = pseg + SEGB;                        // B*WPB f32
  float*  pconf    = ploc + (size_t)Bn*WPB;              // B*WPB f32
  int*    ppos     = (int*)(pconf + (size_t)Bn*WPB);     // B*WPB i32

  // radix-select scratch in the ov_prior region (dead after phaseD):
  unsigned* gcnt0 = (unsigned*)ov_prior;
  float*    gsum0 = (float*)(gcnt0 + (size_t)Bn*4096);
  unsigned* gcnt1 = (unsigned*)(gsum0 + (size_t)Bn*4096);
  float*    gsum1 = (float*)(gcnt1 + (size_t)Bn*4096);
  unsigned* prefix = (unsigned*)(gsum1 + (size_t)Bn*4096);
  int*      krem   = (int*)(prefix + Bn);
  double*   stop0  = (double*)(krem + Bn);   // 8B-aligned

  // only key_obj needs zeroing (atomicMax targets); partials fully written
  hipMemsetAsync(key_obj, 0, (size_t)Bn*On*8, stream);

  seg_kernel   <<<SEGB, 256, 0, stream>>>(att, pseg);
  matchAB_kernel<<<dim3(FBLK, Bn), 256, 0, stream>>>(boxes, ign, priors,
                                                     ov_prior, objinfo, key_obj);
  phaseC_kernel<<<1, 64, 0, stream>>>(key_obj, ov_prior, objinfo);
  phaseD_kernel<<<dim3(DBLK, Bn), 256, 0, stream>>>(odm_locs, odm_scores, boxes, labels,
                                                    priors, ov_prior, objinfo,
                                                    conf_neg, ploc, pconf, ppos);
  npos_kernel<<<1, 64, 0, stream>>>(ppos, n_pos);
  // ov_prior dead from here; reuse as radix scratch
  hipMemsetAsync(gcnt0, 0, 4*(size_t)Bn*4096*sizeof(unsigned), stream);
  histE_kernel<0><<<dim3(CHn, Bn), 256, 0, stream>>>(conf_neg, n_pos, prefix, krem, gcnt0, gsum0);
  scanE_kernel<0><<<Bn, 256, 0, stream>>>(gcnt0, gsum0, n_pos, prefix, krem, stop0, phard);
  histE_kernel<1><<<dim3(CHn, Bn), 256, 0, stream>>>(conf_neg, n_pos, prefix, krem, gcnt1, gsum1);
  scanE_kernel<1><<<Bn, 256, 0, stream>>>(gcnt1, gsum1, n_pos, prefix, krem, stop0, phard);
  final_kernel<<<1, 256, 0, stream>>>(n_pos, pseg, ploc, pconf, phard, out);
}

// Round 20
// 206.900 us; speedup vs baseline: 1.0999x; 1.0262x over previous
//
#include <hip/hip_runtime.h>
#include <math.h>

#define Bn 32
#define Pn 42840
#define On 64
#define NIn 8
#define Cn 11
#define ATT_N (32*56*96)
#define THRESHOLD_F 0.4f
#define THETA_F 0.1f
#define CHn 16
#define CHUNK ((Pn + CHn - 1)/CHn)
#define DBLK 42         /* phaseD blocks per batch */
#define WPB  (DBLK*4)   /* phaseD waves per batch = 168 */
#define SEGB ((ATT_N+255)/256)   /* 672 seg blocks */
#define FP 4            /* priors per thread in matchAB */
#define FBLK ((Pn + 256*FP - 1)/(256*FP))   /* 42 blocks per batch */

// opaque register pin: read-write empty asm -> compiler cannot rematerialize
#define PINF(x) asm volatile("" : "+v"(x))

// ---- seg loss: per-block partial (no atomics) ----
__global__ void seg_kernel(const float* __restrict__ att, float* __restrict__ pseg){
  int i = blockIdx.x*256 + threadIdx.x;
  float v = 0.0f;
  if (i < ATT_N) v = fmaxf(log1pf(-att[i]), -100.0f);
  __shared__ float s[256];
  int t = threadIdx.x;
  s[t]=v; __syncthreads();
  for (int st=128; st>0; st>>=1){ if (t<st) s[t]+=s[t+st]; __syncthreads(); }
  if (t==0) pseg[blockIdx.x] = s[0];
}

// ---- fused match: ONE pass over the O x P iou matrix reduces BOTH axes ----
// row (per-prior argmax over objects) -> ov_prior/objinfo
// col (per-object argmax over priors) -> float butterfly + ballot leader ->
//     LDS atomicMax(skey) -> one global atomicMax per (block, object)
__global__ void __launch_bounds__(256, 4)
matchAB_kernel(const float* __restrict__ boxes,
               const float* __restrict__ ign,
               const float* __restrict__ priors,
               float* __restrict__ ov_prior,
               int* __restrict__ objinfo,
               unsigned long long* __restrict__ key_obj){
  __shared__ float4 sbox[On];
  __shared__ float  sar[On];
  __shared__ float4 ibox[NIn];
  __shared__ float  iar[NIn];
  __shared__ unsigned long long skey[On];
  int b = blockIdx.y, t = threadIdx.x;
  if (t < On){
    float4 v = ((const float4*)boxes)[b*On + t];
    sbox[t]=v; sar[t]=(v.z-v.x)*(v.w-v.y);
    skey[t]=0ull;
  } else if (t < On+NIn){
    int o = t - On;
    float4 v = ((const float4*)ign)[b*NIn + o];
    ibox[o]=v; iar[o]=(v.z-v.x)*(v.w-v.y);
  }
  __syncthreads();
  int p0 = (blockIdx.x*256 + t)*FP;
  bool active = (p0 < Pn);          // Pn%4==0 -> all 4 valid when active
  float px1[FP], py1[FP], px2[FP], py2[FP], pab[FP];
  #pragma unroll
  for (int q=0;q<FP;q++){
    float4 pc = active ? ((const float4*)priors)[p0+q]
                       : make_float4(0.f,0.f,0.f,0.f);
    px1[q]=pc.x - pc.z*0.5f; py1[q]=pc.y - pc.w*0.5f;
    px2[q]=pc.x + pc.z*0.5f; py2[q]=pc.y + pc.w*0.5f;
    pab[q]=(px2[q]-px1[q])*(py2[q]-py1[q]);
    PINF(px1[q]); PINF(py1[q]); PINF(px2[q]); PINF(py2[q]); PINF(pab[q]);
  }
  float best[FP]; int bo[FP];
  #pragma unroll
  for (int q=0;q<FP;q++){ best[q]=-1.0f; bo[q]=0; }
  #pragma unroll 1
  for (int o=0;o<On;o++){
    float4 ob = sbox[o];
    float oar = sar[o];
    float cmax=-1.0f; unsigned cp=0u;
    #pragma unroll
    for (int q=0;q<FP;q++){
      float ltx=fmaxf(ob.x,px1[q]), lty=fmaxf(ob.y,py1[q]);
      float rbx=fminf(ob.z,px2[q]), rby=fminf(ob.w,py2[q]);
      float w=fmaxf(rbx-ltx,0.0f), h=fmaxf(rby-lty,0.0f);
      float inter=w*h;
      float uni=(oar+pab[q])-inter;
      float iou = inter * __builtin_amdgcn_rcpf(uni);
      if (iou > best[q]){ best[q]=iou; bo[q]=o; }   // row argmax, first-occurrence
      if (iou > cmax){ cmax=iou; cp=(unsigned)(p0+q); } // col local, smallest p
    }
    // float-only wave max, then lowest-lane-among-ties = smallest p
    float wm = cmax;
    #pragma unroll
    for (int d=32; d>0; d>>=1)
      wm = fmaxf(wm, __shfl_xor(wm, d, 64));
    unsigned long long ball = __ballot(cmax == wm);
    int leader = __ffsll((long long)ball) - 1;
    if (active && (t & 63) == leader){
      unsigned long long key = ((unsigned long long)__float_as_uint(wm)<<32)
                             | (unsigned long long)(0xFFFFFFFFu - cp);
      atomicMax(&skey[o], key);
    }
  }
  // ignored regions: per-prior max only
  float ib[FP];
  #pragma unroll
  for (int q=0;q<FP;q++) ib[q]=-1.0f;
  #pragma unroll
  for (int j=0;j<NIn;j++){
    float4 jb = ibox[j];
    float jar = iar[j];
    #pragma unroll
    for (int q=0;q<FP;q++){
      float ltx=fmaxf(jb.x,px1[q]), lty=fmaxf(jb.y,py1[q]);
      float rbx=fminf(jb.z,px2[q]), rby=fminf(jb.w,py2[q]);
      float w=fmaxf(rbx-ltx,0.0f), h=fmaxf(rby-lty,0.0f);
      float inter=w*h;
      float uni=(jar+pab[q])-inter;
      ib[q] = fmaxf(ib[q], inter * __builtin_amdgcn_rcpf(uni));
    }
  }
  if (active){
    size_t bp0 = (size_t)b*Pn + p0;
    int in_[FP];
    #pragma unroll
    for (int q=0;q<FP;q++)
      in_[q] = bo[q] | ((ib[q] >= THETA_F) ? 256 : 0);
    *(float4*)(ov_prior + bp0) = make_float4(best[0],best[1],best[2],best[3]);
    *(int4*)(objinfo + bp0)    = make_int4(in_[0],in_[1],in_[2],in_[3]);
  }
  __syncthreads();
  if (t < On) atomicMax(&key_obj[(size_t)b*On + t], skey[t]);
}

// ---- phase C: sequential per-batch scatter (set 1.0; last-write-wins rank) ----
__global__ void phaseC_kernel(const unsigned long long* __restrict__ key_obj,
                              float* __restrict__ ov_prior,
                              int* __restrict__ objinfo){
  int b = threadIdx.x;
  if (b >= Bn) return;
  int rank = -1;
  for (int o=0;o<On;o++){
    unsigned long long k = key_obj[(size_t)b*On+o];
    if ((unsigned)(k>>32) > 0u){            // iou > 0  <=> valid
      rank++;                               // jranks = cumsum(valid)-1
      int p = (int)(0xFFFFFFFFu - (unsigned)(k & 0xFFFFFFFFu));
      size_t bp = (size_t)b*Pn + p;
      ov_prior[bp] = 1.0f;
      objinfo[bp] = (objinfo[bp] & 256) | rank; // ascending o => overwrite == max(jr)
    }
  }
}

// ---- phase D: 4 priors/thread; per-WAVE shuffle reduce; no barriers, no atomics ----
__global__ void __launch_bounds__(256, 4)
phaseD_kernel(const float* __restrict__ odm_locs,
              const float* __restrict__ odm_scores,
              const float* __restrict__ boxes,
              const int* __restrict__ labels,
              const float* __restrict__ priors,
              const float* __restrict__ ov_prior,
              const int* __restrict__ objinfo,
              float* __restrict__ conf_neg,
              float* __restrict__ ploc,
              float* __restrict__ pconf,
              int* __restrict__ ppos){
  int b = blockIdx.y;
  int t = threadIdx.x;
  int p0 = (blockIdx.x*256 + t)*4;
  float locv = 0.0f, confpv = 0.0f; int posv = 0;
  if (p0 < Pn){                           // Pn%4==0 -> all 4 priors valid
    size_t bp0 = (size_t)b*Pn + p0;
    float4 sc4[11];
    const float4* src = (const float4*)(odm_scores + bp0*Cn);  // 16B-aligned
    #pragma unroll
    for (int i=0;i<11;i++) sc4[i] = src[i];
    int4   info4 = *(const int4*)(objinfo + bp0);
    float4 ovp4  = *(const float4*)(ov_prior + bp0);
    const float* sc = (const float*)sc4;   // constant indices only (post-unroll)
    float cn[4];
    #pragma unroll
    for (int j=0;j<4;j++){
      int info = (&info4.x)[j];
      int obj = info & 0xFF;
      bool ignored = (info & 256) != 0;
      int label = labels[b*On + obj];
      if ((&ovp4.x)[j] < THRESHOLD_F) label = 0;
      bool pos = label > 0;
      float m = sc[j*Cn];
      #pragma unroll
      for (int c=1;c<Cn;c++) m = fmaxf(m, sc[j*Cn+c]);
      float se = 0.0f, slab = 0.0f;
      #pragma unroll
      for (int c=0;c<Cn;c++){
        float v = sc[j*Cn+c];
        se += expf(v-m);
        if (c == label) slab = v;          // c is compile-time -> cndmask chain
      }
      float conf = logf(se) - (slab-m);
      cn[j] = (pos || ignored) ? 0.0f : conf;
      if (pos){
        posv += 1; confpv += conf;
        size_t bp = bp0 + j;
        float4 pc = ((const float4*)priors)[p0+j];
        float4 g  = ((const float4*)odm_locs)[bp];
        float cx = g.x*pc.z/10.0f + pc.x;
        float cy = g.y*pc.w/10.0f + pc.y;
        float w  = expf(g.z/5.0f)*pc.z;
        float h  = expf(g.w/5.0f)*pc.w;
        float dx1 = cx - w/2.0f, dy1 = cy - h/2.0f;
        float dx2 = cx + w/2.0f, dy2 = cy + h/2.0f;
        const float* gt = boxes + ((size_t)b*On + obj)*4;
        float gx1=gt[0], gy1=gt[1], gx2=gt[2], gy2=gt[3];
        float ltx=fmaxf(dx1,gx1), lty=fmaxf(dy1,gy1);
        float rbx=fminf(dx2,gx2), rby=fminf(dy2,gy2);
        float iw=fmaxf(rbx-ltx,0.0f), ih=fmaxf(rby-lty,0.0f);
        float inter=iw*ih;
        float ap=(dx2-dx1)*(dy2-dy1);
        float ag=(gx2-gx1)*(gy2-gy1);
        float iou = inter/((ap+ag)-inter);
        float cpx=(dx1+dx2)/2.0f, cpy=(dy1+dy2)/2.0f;
        float cgx=(gx1+gx2)/2.0f, cgy=(gy1+gy2)/2.0f;
        float ddx=cpx-cgx, ddy=cpy-cgy;
        float inter_diag = ddx*ddx + ddy*ddy;
        float cltx=fminf(dx1,gx1), clty=fminf(dy1,gy1);
        float crbx=fmaxf(dx2,gx2), crby=fmaxf(dy2,gy2);
        float odx=crbx-cltx, ody=crby-clty;
        float outer_diag = odx*odx + ody*ody;
        float diou = fminf(fmaxf(iou - inter_diag/outer_diag, -1.0f), 1.0f);
        locv += 1.0f - diou;
      }
    }
    *(float4*)(conf_neg + bp0) = make_float4(cn[0],cn[1],cn[2],cn[3]);
  }
  // per-wave butterfly reduction, lane 0 writes a unique slot -> zero contention
  #pragma unroll
  for (int d=32; d>0; d>>=1){
    locv   += __shfl_xor(locv,   d, 64);
    confpv += __shfl_xor(confpv, d, 64);
    posv   += __shfl_xor(posv,   d, 64);
  }
  if ((t & 63) == 0){
    int widx = b*WPB + (blockIdx.x<<2) + (t>>6);
    ploc[widx]  = locv;
    pconf[widx] = confpv;
    ppos[widx]  = posv;
  }
}

// ---- n_pos reduce ----
__global__ void npos_kernel(const int* __restrict__ ppos, int* __restrict__ n_pos){
  int b = threadIdx.x;
  if (b >= Bn) return;
  int s = 0;
  for (int w=0; w<WPB; w++) s += ppos[b*WPB + w];
  n_pos[b] = s;
}

// ---- phase E: 2-round radix select with per-bin (count,sum) ----
template<int ROUND>
__global__ void histE_kernel(const float* __restrict__ conf_neg,
                             const int* __restrict__ n_pos,
                             const unsigned* __restrict__ prefix,
                             const int* __restrict__ krem_st,
                             unsigned* __restrict__ gcnt,
                             float* __restrict__ gsum){
  int b = blockIdx.y, c = blockIdx.x, t = threadIdx.x;
  if (n_pos[b] <= 0) return;
  if (ROUND==1 && krem_st[b] < 0) return;   // K>=Pn handled in scan0
  __shared__ unsigned hc[4096];
  __shared__ float    hs[4096];
  for (int i=t;i<4096;i+=256){ hc[i]=0u; hs[i]=0.0f; }
  __syncthreads();
  unsigned pref = (ROUND==0)?0u:(prefix[b]>>20);
  const float* cn = conf_neg + (size_t)b*Pn;
  int p0 = c*CHUNK, p1 = min(Pn, p0+CHUNK);
  for (int p=p0+t; p<p1; p+=256){
    float v = cn[p];
    unsigned key = __float_as_uint(v);   // v >= 0 -> uint order == float order
    if (ROUND==0){
      unsigned d = key>>20;
      atomicAdd(&hc[d],1u); atomicAdd(&hs[d],v);
    } else {
      if ((key>>20)==pref){
        unsigned d = (key>>8)&0xFFFu;
        atomicAdd(&hc[d],1u); atomicAdd(&hs[d],v);
      }
    }
  }
  __syncthreads();
  unsigned* gc = gcnt + (size_t)b*4096;
  float*    gs = gsum + (size_t)b*4096;
  for (int i=t;i<4096;i+=256){
    if (hc[i]){ atomicAdd(&gc[i], hc[i]); atomicAdd(&gs[i], hs[i]); }
  }
}

template<int ROUND>
__global__ void scanE_kernel(const unsigned* __restrict__ gcnt,
                             const float* __restrict__ gsum,
                             const int* __restrict__ n_pos,
                             unsigned* __restrict__ prefix,
                             int* __restrict__ krem_st,
                             double* __restrict__ stop0,
                             double* __restrict__ phard){
  int b = blockIdx.x, t = threadIdx.x;
  int K = 2*n_pos[b];
  if (K <= 0){ if (ROUND==0 && t==0) phard[b] = 0.0; return; }
  if (ROUND==1 && krem_st[b] < 0) return;
  const unsigned* gc = gcnt + (size_t)b*4096;
  const float*    gs = gsum + (size_t)b*4096;
  unsigned cnt[16]; float sm[16];
  unsigned ts = 0;
  #pragma unroll
  for (int i=0;i<16;i++){ cnt[i]=gc[t*16+i]; sm[i]=gs[t*16+i]; ts+=cnt[i]; }
  __shared__ unsigned sh[256];
  __shared__ int s_sel;
  __shared__ double sd[256];
  if (t==0) s_sel = -1;
  sh[t]=ts;
  __syncthreads();
  for (int off=1; off<256; off<<=1){
    unsigned v = (t+off<256)? sh[t+off]:0u;   // read (after barrier)
    __syncthreads();
    sh[t]+=v;                                  // write
    __syncthreads();
  }
  if (ROUND==0 && K >= Pn){
    double ds=0.0;
    #pragma unroll
    for (int i=0;i<16;i++) ds += (double)sm[i];
    sd[t]=ds; __syncthreads();
    for (int st=128;st>0;st>>=1){ if(t<st) sd[t]+=sd[t+st]; __syncthreads(); }
    if (t==0){ phard[b]=sd[0]; krem_st[b]=-1; }
    return;
  }
  int krem = (ROUND==0)? K : krem_st[b];
  unsigned incl = sh[t];           // count of keys in bins >= this thread's lowest
  unsigned above = incl - ts;      // count in strictly-higher threads' bins
  if ((int)above < krem && krem <= (int)incl){
    int acc = (int)above;
    #pragma unroll
    for (int i=15;i>=0;i--){
      acc += (int)cnt[i];
      if (acc >= krem){
        unsigned sel = (unsigned)(t*16+i);
        int krem_new = krem - (acc - (int)cnt[i]);
        if (ROUND==0) prefix[b]  = sel<<20;
        else          prefix[b] |= sel<<8;
        krem_st[b] = krem_new;
        s_sel = (int)sel;
        break;
      }
    }
  }
  __syncthreads();
  int sel = s_sel;
  double ds = 0.0;
  #pragma unroll
  for (int i=0;i<16;i++){ int idx=t*16+i; if (idx > sel) ds += (double)sm[i]; }
  sd[t]=ds; __syncthreads();
  for (int st=128;st>0;st>>=1){ if(t<st) sd[t]+=sd[t+st]; __syncthreads(); }
  if (t==0){
    if (ROUND==0) stop0[b] = sd[0];
    else {
      // tie bucket approximated by its midpoint (error << absmax threshold)
      float vmid = __uint_as_float(prefix[b] | 0x80u);
      phard[b] = stop0[b] + sd[0] + (double)krem_st[b] * (double)vmid;
    }
  }
}

// ---- final combine: sum all partial arrays in doubles ----
__global__ void final_kernel(const int* __restrict__ n_pos,
                             const float* __restrict__ pseg,
                             const float* __restrict__ ploc,
                             const float* __restrict__ pconf,
                             const double* __restrict__ phard,
                             float* __restrict__ out){
  int t = threadIdx.x;
  double seg_s=0.0, loc_s=0.0, conf_s=0.0, hard_s=0.0;
  for (int i=t;i<SEGB;i+=256)     seg_s  += (double)pseg[i];
  for (int i=t;i<Bn*WPB;i+=256)   loc_s  += (double)ploc[i];
  for (int i=t;i<Bn*WPB;i+=256)   conf_s += (double)pconf[i];
  for (int i=t;i<Bn;i+=256)       hard_s += phard[i];
  int tp_s = (t < Bn) ? n_pos[t] : 0;
  __shared__ double sd[256];
  __shared__ int    si_[256];
  si_[t]=tp_s;
  sd[t]=seg_s;  __syncthreads();
  for (int st=128;st>0;st>>=1){ if(t<st){ sd[t]+=sd[t+st]; si_[t]+=si_[t+st]; } __syncthreads(); }
  double seg_t = sd[0]; int tp = si_[0];
  __syncthreads();
  sd[t]=loc_s;  __syncthreads();
  for (int st=128;st>0;st>>=1){ if(t<st) sd[t]+=sd[t+st]; __syncthreads(); }
  double loc_t = sd[0];
  __syncthreads();
  sd[t]=conf_s+hard_s; __syncthreads();
  for (int st=128;st>0;st>>=1){ if(t<st) sd[t]+=sd[t+st]; __syncthreads(); }
  double conf_t = sd[0];
  if (t==0){
    float total = (float)tp;
    float conf_loss = (float)conf_t / total;
    float loc_loss  = (float)loc_t / total;
    float seg_loss  = -(float)seg_t;
    out[0] = conf_loss + loc_loss + seg_loss;
  }
}

extern "C" void kernel_launch(void* const* d_in, const int* in_sizes, int n_in,
                              void* d_out, int out_size, void* d_ws, size_t ws_size,
                              hipStream_t stream) {
  const float* odm_locs   = (const float*)d_in[0];
  const float* odm_scores = (const float*)d_in[1];
  const float* att        = (const float*)d_in[2];
  const float* boxes      = (const float*)d_in[3];
  const int*   labels     = (const int*)d_in[4];
  const float* ign        = (const float*)d_in[5];
  const float* priors     = (const float*)d_in[6];
  float* out = (float*)d_out;

  size_t np = (size_t)Bn * Pn;
  float* ov_prior  = (float*)d_ws;                 // B*P f32
  int*   objinfo   = (int*)(ov_prior + np);        // B*P i32
  float* conf_neg  = (float*)(objinfo + np);       // B*P f32
  unsigned long long* key_obj = (unsigned long long*)(conf_neg + np); // B*O u64
  double* phard    = (double*)(key_obj + (size_t)Bn*On); // Bn f64
  int*    n_pos    = (int*)(phard + Bn);                 // B i32
  float*  pseg     = (float*)(n_pos + Bn);               // SEGB f32
  float*  ploc     = pseg + SEGB;                        // B*WPB f32
  float*  pconf    = ploc + (size_t)Bn*WPB;              // B*WPB f32
  int*    ppos     = (int*)(pconf + (size_t)Bn*WPB);     // B*WPB i32

  // radix-select scratch in the ov_prior region (dead after phaseD):
  unsigned* gcnt0 = (unsigned*)ov_prior;
  float*    gsum0 = (float*)(gcnt0 + (size_t)Bn*4096);
  unsigned* gcnt1 = (unsigned*)(gsum0 + (size_t)Bn*4096);
  float*    gsum1 = (float*)(gcnt1 + (size_t)Bn*4096);
  unsigned* prefix = (unsigned*)(gsum1 + (size_t)Bn*4096);
  int*      krem   = (int*)(prefix + Bn);
  double*   stop0  = (double*)(krem + Bn);   // 8B-aligned

  // only key_obj needs zeroing (atomicMax targets); partials fully written
  hipMemsetAsync(key_obj, 0, (size_t)Bn*On*8, stream);

  seg_kernel   <<<SEGB, 256, 0, stream>>>(att, pseg);
  matchAB_kernel<<<dim3(FBLK, Bn), 256, 0, stream>>>(boxes, ign, priors,
                                                     ov_prior, objinfo, key_obj);
  phaseC_kernel<<<1, 64, 0, stream>>>(key_obj, ov_prior, objinfo);
  phaseD_kernel<<<dim3(DBLK, Bn), 256, 0, stream>>>(odm_locs, odm_scores, boxes, labels,
                                                    priors, ov_prior, objinfo,
                                                    conf_neg, ploc, pconf, ppos);
  npos_kernel<<<1, 64, 0, stream>>>(ppos, n_pos);
  // ov_prior dead from here; reuse as radix scratch
  hipMemsetAsync(gcnt0, 0, 4*(size_t)Bn*4096*sizeof(unsigned), stream);
  histE_kernel<0><<<dim3(CHn, Bn), 256, 0, stream>>>(conf_neg, n_pos, prefix, krem, gcnt0, gsum0);
  scanE_kernel<0><<<Bn, 256, 0, stream>>>(gcnt0, gsum0, n_pos, prefix, krem, stop0, phard);
  histE_kernel<1><<<dim3(CHn, Bn), 256, 0, stream>>>(conf_neg, n_pos, prefix, krem, gcnt1, gsum1);
  scanE_kernel<1><<<Bn, 256, 0, stream>>>(gcnt1, gsum1, n_pos, prefix, krem, stop0, phard);
  final_kernel<<<1, 256, 0, stream>>>(n_pos, pseg, ploc, pconf, phard, out);
}

// Round 21
// 176.504 us; speedup vs baseline: 1.2893x; 1.1722x over previous
//
#include <hip/hip_runtime.h>
#include <math.h>

#define Bn 32
#define Pn 42840
#define On 64
#define NIn 8
#define Cn 11
#define ATT_N (32*56*96)
#define THRESHOLD_F 0.4f
#define THETA_F 0.1f
#define CHn 16
#define CHUNK ((Pn + CHn - 1)/CHn)
#define DBLK 42         /* phaseD blocks per batch */
#define WPB  (DBLK*4)   /* phaseD waves per batch = 168 */
#define FP 4            /* priors per thread in matchAB */
#define FBLK ((Pn + 256*FP - 1)/(256*FP))   /* 42 blocks per batch */

// opaque register pin: read-write empty asm -> compiler cannot rematerialize
#define PINF(x) asm volatile("" : "+v"(x))

// ---- fused match: ONE pass over the O x P iou matrix reduces BOTH axes ----
__global__ void __launch_bounds__(256, 4)
matchAB_kernel(const float* __restrict__ boxes,
               const float* __restrict__ ign,
               const float* __restrict__ priors,
               float* __restrict__ ov_prior,
               int* __restrict__ objinfo,
               unsigned long long* __restrict__ key_obj){
  __shared__ float4 sbox[On];
  __shared__ float  sar[On];
  __shared__ float4 ibox[NIn];
  __shared__ float  iar[NIn];
  __shared__ unsigned long long skey[On];
  int b = blockIdx.y, t = threadIdx.x;
  if (t < On){
    float4 v = ((const float4*)boxes)[b*On + t];
    sbox[t]=v; sar[t]=(v.z-v.x)*(v.w-v.y);
    skey[t]=0ull;
  } else if (t < On+NIn){
    int o = t - On;
    float4 v = ((const float4*)ign)[b*NIn + o];
    ibox[o]=v; iar[o]=(v.z-v.x)*(v.w-v.y);
  }
  __syncthreads();
  int p0 = (blockIdx.x*256 + t)*FP;
  bool active = (p0 < Pn);          // Pn%4==0 -> all 4 valid when active
  float px1[FP], py1[FP], px2[FP], py2[FP], pab[FP];
  #pragma unroll
  for (int q=0;q<FP;q++){
    float4 pc = active ? ((const float4*)priors)[p0+q]
                       : make_float4(0.f,0.f,0.f,0.f);
    px1[q]=pc.x - pc.z*0.5f; py1[q]=pc.y - pc.w*0.5f;
    px2[q]=pc.x + pc.z*0.5f; py2[q]=pc.y + pc.w*0.5f;
    pab[q]=(px2[q]-px1[q])*(py2[q]-py1[q]);
    PINF(px1[q]); PINF(py1[q]); PINF(px2[q]); PINF(py2[q]); PINF(pab[q]);
  }
  float best[FP]; int bo[FP];
  #pragma unroll
  for (int q=0;q<FP;q++){ best[q]=-1.0f; bo[q]=0; }
  #pragma unroll 1
  for (int o=0;o<On;o++){
    float4 ob = sbox[o];
    float oar = sar[o];
    float cmax=-1.0f; unsigned cp=0u;
    #pragma unroll
    for (int q=0;q<FP;q++){
      float ltx=fmaxf(ob.x,px1[q]), lty=fmaxf(ob.y,py1[q]);
      float rbx=fminf(ob.z,px2[q]), rby=fminf(ob.w,py2[q]);
      float w=fmaxf(rbx-ltx,0.0f), h=fmaxf(rby-lty,0.0f);
      float inter=w*h;
      float uni=(oar+pab[q])-inter;
      float iou = inter * __builtin_amdgcn_rcpf(uni);
      if (iou > best[q]){ best[q]=iou; bo[q]=o; }   // row argmax, first-occurrence
      if (iou > cmax){ cmax=iou; cp=(unsigned)(p0+q); } // col local, smallest p
    }
    // float-only wave max, then lowest-lane-among-ties = smallest p
    float wm = cmax;
    #pragma unroll
    for (int d=32; d>0; d>>=1)
      wm = fmaxf(wm, __shfl_xor(wm, d, 64));
    unsigned long long ball = __ballot(cmax == wm);
    int leader = __ffsll((long long)ball) - 1;
    if (active && (t & 63) == leader){
      unsigned long long key = ((unsigned long long)__float_as_uint(wm)<<32)
                             | (unsigned long long)(0xFFFFFFFFu - cp);
      atomicMax(&skey[o], key);
    }
  }
  // ignored regions: per-prior max only
  float ib[FP];
  #pragma unroll
  for (int q=0;q<FP;q++) ib[q]=-1.0f;
  #pragma unroll
  for (int j=0;j<NIn;j++){
    float4 jb = ibox[j];
    float jar = iar[j];
    #pragma unroll
    for (int q=0;q<FP;q++){
      float ltx=fmaxf(jb.x,px1[q]), lty=fmaxf(jb.y,py1[q]);
      float rbx=fminf(jb.z,px2[q]), rby=fminf(jb.w,py2[q]);
      float w=fmaxf(rbx-ltx,0.0f), h=fmaxf(rby-lty,0.0f);
      float inter=w*h;
      float uni=(jar+pab[q])-inter;
      ib[q] = fmaxf(ib[q], inter * __builtin_amdgcn_rcpf(uni));
    }
  }
  if (active){
    size_t bp0 = (size_t)b*Pn + p0;
    int in_[FP];
    #pragma unroll
    for (int q=0;q<FP;q++)
      in_[q] = bo[q] | ((ib[q] >= THETA_F) ? 256 : 0);
    *(float4*)(ov_prior + bp0) = make_float4(best[0],best[1],best[2],best[3]);
    *(int4*)(objinfo + bp0)    = make_int4(in_[0],in_[1],in_[2],in_[3]);
  }
  __syncthreads();
  if (t < On) atomicMax(&key_obj[(size_t)b*On + t], skey[t]);
}

// ---- phase C: ballot-rank scatter (== sequential cumsum + last-write-wins) ----
__global__ void phaseC_kernel(const unsigned long long* __restrict__ key_obj,
                              float* __restrict__ ov_prior,
                              int* __restrict__ objinfo){
  int b = blockIdx.x, o = threadIdx.x;   // 64 threads = 1 wave
  unsigned long long k = key_obj[(size_t)b*On + o];
  bool valid = (unsigned)(k>>32) > 0u;
  unsigned long long ball = __ballot(valid);
  int rank = (int)__popcll(ball & ((1ull<<o) - 1ull));  // = cumsum(valid)-1 at o
  if (valid){
    int p = (int)(0xFFFFFFFFu - (unsigned)(k & 0xFFFFFFFFu));
    size_t bp = (size_t)b*Pn + p;
    ov_prior[bp] = 1.0f;
    int old = objinfo[bp];                 // bit 256 invariant under the max below
    atomicMax(&objinfo[bp], (old & 256) | rank); // ranks ascend with o => max == last
  }
}

// ---- phase D: 4 priors/thread + folded seg loss; per-WAVE shuffle reduce ----
__global__ void __launch_bounds__(256, 4)
phaseD_kernel(const float* __restrict__ odm_locs,
              const float* __restrict__ odm_scores,
              const float* __restrict__ boxes,
              const int* __restrict__ labels,
              const float* __restrict__ priors,
              const float* __restrict__ ov_prior,
              const int* __restrict__ objinfo,
              const float* __restrict__ att,
              float* __restrict__ conf_neg,
              float* __restrict__ ploc,
              float* __restrict__ pconf,
              int* __restrict__ ppos,
              float* __restrict__ pseg){
  int b = blockIdx.y;
  int t = threadIdx.x;
  // folded seg: phaseD has 1344*256 = 344064 threads >= ATT_N = 172032
  int gid = (b*DBLK + blockIdx.x)*256 + t;
  float segv = 0.0f;
  if (gid < ATT_N) segv = fmaxf(log1pf(-att[gid]), -100.0f);
  int p0 = (blockIdx.x*256 + t)*4;
  float locv = 0.0f, confpv = 0.0f; int posv = 0;
  if (p0 < Pn){                           // Pn%4==0 -> all 4 priors valid
    size_t bp0 = (size_t)b*Pn + p0;
    float4 sc4[11];
    const float4* src = (const float4*)(odm_scores + bp0*Cn);  // 16B-aligned
    #pragma unroll
    for (int i=0;i<11;i++) sc4[i] = src[i];
    int4   info4 = *(const int4*)(objinfo + bp0);
    float4 ovp4  = *(const float4*)(ov_prior + bp0);
    const float* sc = (const float*)sc4;   // constant indices only (post-unroll)
    float cn[4];
    #pragma unroll
    for (int j=0;j<4;j++){
      int info = (&info4.x)[j];
      int obj = info & 0xFF;
      bool ignored = (info & 256) != 0;
      int label = labels[b*On + obj];
      if ((&ovp4.x)[j] < THRESHOLD_F) label = 0;
      bool pos = label > 0;
      float m = sc[j*Cn];
      #pragma unroll
      for (int c=1;c<Cn;c++) m = fmaxf(m, sc[j*Cn+c]);
      float se = 0.0f, slab = 0.0f;
      #pragma unroll
      for (int c=0;c<Cn;c++){
        float v = sc[j*Cn+c];
        se += expf(v-m);
        if (c == label) slab = v;          // c is compile-time -> cndmask chain
      }
      float conf = logf(se) - (slab-m);
      cn[j] = (pos || ignored) ? 0.0f : conf;
      if (pos){
        posv += 1; confpv += conf;
        size_t bp = bp0 + j;
        float4 pc = ((const float4*)priors)[p0+j];
        float4 g  = ((const float4*)odm_locs)[bp];
        float cx = g.x*pc.z/10.0f + pc.x;
        float cy = g.y*pc.w/10.0f + pc.y;
        float w  = expf(g.z/5.0f)*pc.z;
        float h  = expf(g.w/5.0f)*pc.w;
        float dx1 = cx - w/2.0f, dy1 = cy - h/2.0f;
        float dx2 = cx + w/2.0f, dy2 = cy + h/2.0f;
        const float* gt = boxes + ((size_t)b*On + obj)*4;
        float gx1=gt[0], gy1=gt[1], gx2=gt[2], gy2=gt[3];
        float ltx=fmaxf(dx1,gx1), lty=fmaxf(dy1,gy1);
        float rbx=fminf(dx2,gx2), rby=fminf(dy2,gy2);
        float iw=fmaxf(rbx-ltx,0.0f), ih=fmaxf(rby-lty,0.0f);
        float inter=iw*ih;
        float ap=(dx2-dx1)*(dy2-dy1);
        float ag=(gx2-gx1)*(gy2-gy1);
        float iou = inter/((ap+ag)-inter);
        float cpx=(dx1+dx2)/2.0f, cpy=(dy1+dy2)/2.0f;
        float cgx=(gx1+gx2)/2.0f, cgy=(gy1+gy2)/2.0f;
        float ddx=cpx-cgx, ddy=cpy-cgy;
        float inter_diag = ddx*ddx + ddy*ddy;
        float cltx=fminf(dx1,gx1), clty=fminf(dy1,gy1);
        float crbx=fmaxf(dx2,gx2), crby=fmaxf(dy2,gy2);
        float odx=crbx-cltx, ody=crby-clty;
        float outer_diag = odx*odx + ody*ody;
        float diou = fminf(fmaxf(iou - inter_diag/outer_diag, -1.0f), 1.0f);
        locv += 1.0f - diou;
      }
    }
    *(float4*)(conf_neg + bp0) = make_float4(cn[0],cn[1],cn[2],cn[3]);
  }
  // per-wave butterfly reduction, lane 0 writes a unique slot -> zero contention
  #pragma unroll
  for (int d=32; d>0; d>>=1){
    locv   += __shfl_xor(locv,   d, 64);
    confpv += __shfl_xor(confpv, d, 64);
    posv   += __shfl_xor(posv,   d, 64);
    segv   += __shfl_xor(segv,   d, 64);
  }
  if ((t & 63) == 0){
    int widx = b*WPB + (blockIdx.x<<2) + (t>>6);
    ploc[widx]  = locv;
    pconf[widx] = confpv;
    ppos[widx]  = posv;
    pseg[widx]  = segv;
  }
}

// ---- phase E: 2-round radix select with per-bin (count,sum) ----
template<int ROUND>
__global__ void histE_kernel(const float* __restrict__ conf_neg,
                             const int* __restrict__ n_pos,
                             const unsigned* __restrict__ prefix,
                             const int* __restrict__ krem_st,
                             unsigned* __restrict__ gcnt,
                             float* __restrict__ gsum){
  int b = blockIdx.y, c = blockIdx.x, t = threadIdx.x;
  if (ROUND==1){
    if (n_pos[b] <= 0) return;
    if (krem_st[b] < 0) return;   // K>=Pn handled in scan0
  }
  __shared__ unsigned hc[4096];
  __shared__ float    hs[4096];
  for (int i=t;i<4096;i+=256){ hc[i]=0u; hs[i]=0.0f; }
  __syncthreads();
  unsigned pref = (ROUND==0)?0u:(prefix[b]>>20);
  const float* cn = conf_neg + (size_t)b*Pn;
  int p0 = c*CHUNK, p1 = min(Pn, p0+CHUNK);
  for (int p=p0+t; p<p1; p+=256){
    float v = cn[p];
    unsigned key = __float_as_uint(v);   // v >= 0 -> uint order == float order
    if (ROUND==0){
      unsigned d = key>>20;
      atomicAdd(&hc[d],1u); atomicAdd(&hs[d],v);
    } else {
      if ((key>>20)==pref){
        unsigned d = (key>>8)&0xFFFu;
        atomicAdd(&hc[d],1u); atomicAdd(&hs[d],v);
      }
    }
  }
  __syncthreads();
  unsigned* gc = gcnt + (size_t)b*4096;
  float*    gs = gsum + (size_t)b*4096;
  for (int i=t;i<4096;i+=256){
    if (hc[i]){ atomicAdd(&gc[i], hc[i]); atomicAdd(&gs[i], hs[i]); }
  }
}

template<int ROUND>
__global__ void scanE_kernel(const unsigned* __restrict__ gcnt,
                             const float* __restrict__ gsum,
                             const int* __restrict__ ppos,
                             int* __restrict__ n_pos,
                             unsigned* __restrict__ prefix,
                             int* __restrict__ krem_st,
                             double* __restrict__ stop0,
                             double* __restrict__ phard){
  int b = blockIdx.x, t = threadIdx.x;
  __shared__ unsigned sh[256];
  __shared__ int s_sel;
  __shared__ double sd[256];
  int K;
  if (ROUND==0){
    // fold n_pos reduce into scan0: sum this batch's WPB wave partials
    sh[t] = (t < WPB) ? (unsigned)ppos[b*WPB + t] : 0u;
    __syncthreads();
    for (int st=128; st>0; st>>=1){ if (t<st) sh[t]+=sh[t+st]; __syncthreads(); }
    if (t==0) n_pos[b] = (int)sh[0];
    K = 2*(int)sh[0];
    __syncthreads();
  } else {
    K = 2*n_pos[b];
  }
  if (K <= 0){ if (ROUND==0 && t==0){ phard[b] = 0.0; krem_st[b] = -1; } return; }
  if (ROUND==1 && krem_st[b] < 0) return;
  const unsigned* gc = gcnt + (size_t)b*4096;
  const float*    gs = gsum + (size_t)b*4096;
  unsigned cnt[16]; float sm[16];
  unsigned ts = 0;
  #pragma unroll
  for (int i=0;i<16;i++){ cnt[i]=gc[t*16+i]; sm[i]=gs[t*16+i]; ts+=cnt[i]; }
  if (t==0) s_sel = -1;
  sh[t]=ts;
  __syncthreads();
  for (int off=1; off<256; off<<=1){
    unsigned v = (t+off<256)? sh[t+off]:0u;   // read (after barrier)
    __syncthreads();
    sh[t]+=v;                                  // write
    __syncthreads();
  }
  if (ROUND==0 && K >= Pn){
    double ds=0.0;
    #pragma unroll
    for (int i=0;i<16;i++) ds += (double)sm[i];
    sd[t]=ds; __syncthreads();
    for (int st=128;st>0;st>>=1){ if(t<st) sd[t]+=sd[t+st]; __syncthreads(); }
    if (t==0){ phard[b]=sd[0]; krem_st[b]=-1; }
    return;
  }
  int krem = (ROUND==0)? K : krem_st[b];
  unsigned incl = sh[t];           // count of keys in bins >= this thread's lowest
  unsigned above = incl - ts;      // count in strictly-higher threads' bins
  if ((int)above < krem && krem <= (int)incl){
    int acc = (int)above;
    #pragma unroll
    for (int i=15;i>=0;i--){
      acc += (int)cnt[i];
      if (acc >= krem){
        unsigned sel = (unsigned)(t*16+i);
        int krem_new = krem - (acc - (int)cnt[i]);
        if (ROUND==0) prefix[b]  = sel<<20;
        else          prefix[b] |= sel<<8;
        krem_st[b] = krem_new;
        s_sel = (int)sel;
        break;
      }
    }
  }
  __syncthreads();
  int sel = s_sel;
  double ds = 0.0;
  #pragma unroll
  for (int i=0;i<16;i++){ int idx=t*16+i; if (idx > sel) ds += (double)sm[i]; }
  sd[t]=ds; __syncthreads();
  for (int st=128;st>0;st>>=1){ if(t<st) sd[t]+=sd[t+st]; __syncthreads(); }
  if (t==0){
    if (ROUND==0) stop0[b] = sd[0];
    else {
      // tie bucket approximated by its midpoint (error << absmax threshold)
      float vmid = __uint_as_float(prefix[b] | 0x80u);
      phard[b] = stop0[b] + sd[0] + (double)krem_st[b] * (double)vmid;
    }
  }
}

// ---- final combine: sum all partial arrays in doubles ----
__global__ void final_kernel(const int* __restrict__ n_pos,
                             const float* __restrict__ pseg,
                             const float* __restrict__ ploc,
                             const float* __restrict__ pconf,
                             const double* __restrict__ phard,
                             float* __restrict__ out){
  int t = threadIdx.x;
  double seg_s=0.0, loc_s=0.0, conf_s=0.0, hard_s=0.0;
  for (int i=t;i<Bn*WPB;i+=256)   seg_s  += (double)pseg[i];
  for (int i=t;i<Bn*WPB;i+=256)   loc_s  += (double)ploc[i];
  for (int i=t;i<Bn*WPB;i+=256)   conf_s += (double)pconf[i];
  for (int i=t;i<Bn;i+=256)       hard_s += phard[i];
  int tp_s = (t < Bn) ? n_pos[t] : 0;
  __shared__ double sd[256];
  __shared__ int    si_[256];
  si_[t]=tp_s;
  sd[t]=seg_s;  __syncthreads();
  for (int st=128;st>0;st>>=1){ if(t<st){ sd[t]+=sd[t+st]; si_[t]+=si_[t+st]; } __syncthreads(); }
  double seg_t = sd[0]; int tp = si_[0];
  __syncthreads();
  sd[t]=loc_s;  __syncthreads();
  for (int st=128;st>0;st>>=1){ if(t<st) sd[t]+=sd[t+st]; __syncthreads(); }
  double loc_t = sd[0];
  __syncthreads();
  sd[t]=conf_s+hard_s; __syncthreads();
  for (int st=128;st>0;st>>=1){ if(t<st) sd[t]+=sd[t+st]; __syncthreads(); }
  double conf_t = sd[0];
  if (t==0){
    float total = (float)tp;
    float conf_loss = (float)conf_t / total;
    float loc_loss  = (float)loc_t / total;
    float seg_loss  = -(float)seg_t;
    out[0] = conf_loss + loc_loss + seg_loss;
  }
}

extern "C" void kernel_launch(void* const* d_in, const int* in_sizes, int n_in,
                              void* d_out, int out_size, void* d_ws, size_t ws_size,
                              hipStream_t stream) {
  const float* odm_locs   = (const float*)d_in[0];
  const float* odm_scores = (const float*)d_in[1];
  const float* att        = (const float*)d_in[2];
  const float* boxes      = (const float*)d_in[3];
  const int*   labels     = (const int*)d_in[4];
  const float* ign        = (const float*)d_in[5];
  const float* priors     = (const float*)d_in[6];
  float* out = (float*)d_out;

  size_t np = (size_t)Bn * Pn;
  float* ov_prior  = (float*)d_ws;                 // B*P f32
  int*   objinfo   = (int*)(ov_prior + np);        // B*P i32
  float* conf_neg  = (float*)(objinfo + np);       // B*P f32
  unsigned long long* key_obj = (unsigned long long*)(conf_neg + np); // B*O u64
  double* phard    = (double*)(key_obj + (size_t)Bn*On); // Bn f64
  int*    n_pos    = (int*)(phard + Bn);                 // B i32
  float*  pseg     = (float*)(n_pos + Bn);               // B*WPB f32
  float*  ploc     = pseg + (size_t)Bn*WPB;              // B*WPB f32
  float*  pconf    = ploc + (size_t)Bn*WPB;              // B*WPB f32
  int*    ppos     = (int*)(pconf + (size_t)Bn*WPB);     // B*WPB i32

  // radix-select scratch in the ov_prior region (dead after phaseD):
  unsigned* gcnt0 = (unsigned*)ov_prior;
  float*    gsum0 = (float*)(gcnt0 + (size_t)Bn*4096);
  unsigned* gcnt1 = (unsigned*)(gsum0 + (size_t)Bn*4096);
  float*    gsum1 = (float*)(gcnt1 + (size_t)Bn*4096);
  unsigned* prefix = (unsigned*)(gsum1 + (size_t)Bn*4096);
  int*      krem   = (int*)(prefix + Bn);
  double*   stop0  = (double*)(krem + Bn);   // 8B-aligned

  // only key_obj needs zeroing (atomicMax targets); partials fully written
  hipMemsetAsync(key_obj, 0, (size_t)Bn*On*8, stream);

  matchAB_kernel<<<dim3(FBLK, Bn), 256, 0, stream>>>(boxes, ign, priors,
                                                     ov_prior, objinfo, key_obj);
  phaseC_kernel<<<Bn, 64, 0, stream>>>(key_obj, ov_prior, objinfo);
  phaseD_kernel<<<dim3(DBLK, Bn), 256, 0, stream>>>(odm_locs, odm_scores, boxes, labels,
                                                    priors, ov_prior, objinfo, att,
                                                    conf_neg, ploc, pconf, ppos, pseg);
  // ov_prior dead from here; reuse as radix scratch
  hipMemsetAsync(gcnt0, 0, 4*(size_t)Bn*4096*sizeof(unsigned), stream);
  histE_kernel<0><<<dim3(CHn, Bn), 256, 0, stream>>>(conf_neg, n_pos, prefix, krem, gcnt0, gsum0);
  scanE_kernel<0><<<Bn, 256, 0, stream>>>(gcnt0, gsum0, ppos, n_pos, prefix, krem, stop0, phard);
  histE_kernel<1><<<dim3(CHn, Bn), 256, 0, stream>>>(conf_neg, n_pos, prefix, krem, gcnt1, gsum1);
  scanE_kernel<1><<<Bn, 256, 0, stream>>>(gcnt1, gsum1, ppos, n_pos, prefix, krem, stop0, phard);
  final_kernel<<<1, 256, 0, stream>>>(n_pos, pseg, ploc, pconf, phard, out);
}

// Round 22
// 176.062 us; speedup vs baseline: 1.2925x; 1.0025x over previous
//
#include <hip/hip_runtime.h>
#include <math.h>

#define Bn 32
#define Pn 42840
#define On 64
#define NIn 8
#define Cn 11
#define ATT_N (32*56*96)
#define THRESHOLD_F 0.4f
#define THETA_F 0.1f
#define CHn 16
#define CHUNK ((Pn + CHn - 1)/CHn)
#define DBLK 42         /* phaseD blocks per batch */
#define WPB  (DBLK*4)   /* phaseD waves per batch = 168 */
#define FP 4            /* priors per thread in matchAB */
#define FBLK ((Pn + 256*FP - 1)/(256*FP))   /* 42 blocks per batch */

// opaque register pin: read-write empty asm -> compiler cannot rematerialize
#define PINF(x) asm volatile("" : "+v"(x))

// ---- fused match: ONE pass over the O x P iou matrix reduces BOTH axes ----
// column reduction batched 4 objects at a time: the 4 butterflies are
// independent -> their 6-step shuffle chains interleave (ILP hides latency)
__global__ void __launch_bounds__(256, 4)
matchAB_kernel(const float* __restrict__ boxes,
               const float* __restrict__ ign,
               const float* __restrict__ priors,
               float* __restrict__ ov_prior,
               int* __restrict__ objinfo,
               unsigned long long* __restrict__ key_obj){
  __shared__ float4 sbox[On];
  __shared__ float  sar[On];
  __shared__ float4 ibox[NIn];
  __shared__ float  iar[NIn];
  __shared__ unsigned long long skey[On];
  int b = blockIdx.y, t = threadIdx.x;
  if (t < On){
    float4 v = ((const float4*)boxes)[b*On + t];
    sbox[t]=v; sar[t]=(v.z-v.x)*(v.w-v.y);
    skey[t]=0ull;
  } else if (t < On+NIn){
    int o = t - On;
    float4 v = ((const float4*)ign)[b*NIn + o];
    ibox[o]=v; iar[o]=(v.z-v.x)*(v.w-v.y);
  }
  __syncthreads();
  int p0 = (blockIdx.x*256 + t)*FP;
  bool active = (p0 < Pn);          // Pn%4==0 -> all 4 valid when active
  float px1[FP], py1[FP], px2[FP], py2[FP], pab[FP];
  #pragma unroll
  for (int q=0;q<FP;q++){
    float4 pc = active ? ((const float4*)priors)[p0+q]
                       : make_float4(0.f,0.f,0.f,0.f);
    px1[q]=pc.x - pc.z*0.5f; py1[q]=pc.y - pc.w*0.5f;
    px2[q]=pc.x + pc.z*0.5f; py2[q]=pc.y + pc.w*0.5f;
    pab[q]=(px2[q]-px1[q])*(py2[q]-py1[q]);
    PINF(px1[q]); PINF(py1[q]); PINF(px2[q]); PINF(py2[q]); PINF(pab[q]);
  }
  float best[FP]; int bo[FP];
  #pragma unroll
  for (int q=0;q<FP;q++){ best[q]=-1.0f; bo[q]=0; }
  #pragma unroll 1
  for (int og=0; og<On/4; og++){
    float cmax[4]; unsigned cp[4];
    #pragma unroll
    for (int jo=0;jo<4;jo++){
      int o = og*4 + jo;
      float4 ob = sbox[o];
      float oar = sar[o];
      cmax[jo]=-1.0f; cp[jo]=0u;
      #pragma unroll
      for (int q=0;q<FP;q++){
        float ltx=fmaxf(ob.x,px1[q]), lty=fmaxf(ob.y,py1[q]);
        float rbx=fminf(ob.z,px2[q]), rby=fminf(ob.w,py2[q]);
        float w=fmaxf(rbx-ltx,0.0f), h=fmaxf(rby-lty,0.0f);
        float inter=w*h;
        float uni=(oar+pab[q])-inter;
        float iou = inter * __builtin_amdgcn_rcpf(uni);
        if (iou > best[q]){ best[q]=iou; bo[q]=o; }     // row argmax, first-occ.
        if (iou > cmax[jo]){ cmax[jo]=iou; cp[jo]=(unsigned)(p0+q); }
      }
    }
    // 4 interleaved wave-max butterflies (independent chains)
    float wm[4];
    #pragma unroll
    for (int jo=0;jo<4;jo++) wm[jo]=cmax[jo];
    #pragma unroll
    for (int d=32; d>0; d>>=1){
      #pragma unroll
      for (int jo=0;jo<4;jo++)
        wm[jo] = fmaxf(wm[jo], __shfl_xor(wm[jo], d, 64));
    }
    #pragma unroll
    for (int jo=0;jo<4;jo++){
      unsigned long long ball = __ballot(cmax[jo] == wm[jo]);
      int leader = __ffsll((long long)ball) - 1;
      if (active && (t & 63) == leader){
        unsigned long long key = ((unsigned long long)__float_as_uint(wm[jo])<<32)
                               | (unsigned long long)(0xFFFFFFFFu - cp[jo]);
        atomicMax(&skey[og*4+jo], key);
      }
    }
  }
  // ignored regions: per-prior max only
  float ib[FP];
  #pragma unroll
  for (int q=0;q<FP;q++) ib[q]=-1.0f;
  #pragma unroll
  for (int j=0;j<NIn;j++){
    float4 jb = ibox[j];
    float jar = iar[j];
    #pragma unroll
    for (int q=0;q<FP;q++){
      float ltx=fmaxf(jb.x,px1[q]), lty=fmaxf(jb.y,py1[q]);
      float rbx=fminf(jb.z,px2[q]), rby=fminf(jb.w,py2[q]);
      float w=fmaxf(rbx-ltx,0.0f), h=fmaxf(rby-lty,0.0f);
      float inter=w*h;
      float uni=(jar+pab[q])-inter;
      ib[q] = fmaxf(ib[q], inter * __builtin_amdgcn_rcpf(uni));
    }
  }
  if (active){
    size_t bp0 = (size_t)b*Pn + p0;
    int in_[FP];
    #pragma unroll
    for (int q=0;q<FP;q++)
      in_[q] = bo[q] | ((ib[q] >= THETA_F) ? 256 : 0);
    *(float4*)(ov_prior + bp0) = make_float4(best[0],best[1],best[2],best[3]);
    *(int4*)(objinfo + bp0)    = make_int4(in_[0],in_[1],in_[2],in_[3]);
  }
  __syncthreads();
  if (t < On) atomicMax(&key_obj[(size_t)b*On + t], skey[t]);
}

// ---- phase C: ballot-rank scatter (== sequential cumsum + last-write-wins) ----
__global__ void phaseC_kernel(const unsigned long long* __restrict__ key_obj,
                              float* __restrict__ ov_prior,
                              int* __restrict__ objinfo){
  int b = blockIdx.x, o = threadIdx.x;   // 64 threads = 1 wave
  unsigned long long k = key_obj[(size_t)b*On + o];
  bool valid = (unsigned)(k>>32) > 0u;
  unsigned long long ball = __ballot(valid);
  int rank = (int)__popcll(ball & ((1ull<<o) - 1ull));  // = cumsum(valid)-1 at o
  if (valid){
    int p = (int)(0xFFFFFFFFu - (unsigned)(k & 0xFFFFFFFFu));
    size_t bp = (size_t)b*Pn + p;
    ov_prior[bp] = 1.0f;
    int old = objinfo[bp];                 // bit 256 invariant under the max below
    atomicMax(&objinfo[bp], (old & 256) | rank); // ranks ascend with o => max == last
  }
}

// ---- phase D: 4 priors/thread + folded seg loss; per-WAVE shuffle reduce ----
__global__ void __launch_bounds__(256, 4)
phaseD_kernel(const float* __restrict__ odm_locs,
              const float* __restrict__ odm_scores,
              const float* __restrict__ boxes,
              const int* __restrict__ labels,
              const float* __restrict__ priors,
              const float* __restrict__ ov_prior,
              const int* __restrict__ objinfo,
              const float* __restrict__ att,
              float* __restrict__ conf_neg,
              float* __restrict__ ploc,
              float* __restrict__ pconf,
              int* __restrict__ ppos,
              float* __restrict__ pseg){
  int b = blockIdx.y;
  int t = threadIdx.x;
  // folded seg: phaseD has 1344*256 = 344064 threads >= ATT_N = 172032
  int gid = (b*DBLK + blockIdx.x)*256 + t;
  float segv = 0.0f;
  if (gid < ATT_N) segv = fmaxf(log1pf(-att[gid]), -100.0f);
  int p0 = (blockIdx.x*256 + t)*4;
  float locv = 0.0f, confpv = 0.0f; int posv = 0;
  if (p0 < Pn){                           // Pn%4==0 -> all 4 priors valid
    size_t bp0 = (size_t)b*Pn + p0;
    float4 sc4[11];
    const float4* src = (const float4*)(odm_scores + bp0*Cn);  // 16B-aligned
    #pragma unroll
    for (int i=0;i<11;i++) sc4[i] = src[i];
    int4   info4 = *(const int4*)(objinfo + bp0);
    float4 ovp4  = *(const float4*)(ov_prior + bp0);
    const float* sc = (const float*)sc4;   // constant indices only (post-unroll)
    float cn[4];
    #pragma unroll
    for (int j=0;j<4;j++){
      int info = (&info4.x)[j];
      int obj = info & 0xFF;
      bool ignored = (info & 256) != 0;
      int label = labels[b*On + obj];
      if ((&ovp4.x)[j] < THRESHOLD_F) label = 0;
      bool pos = label > 0;
      float m = sc[j*Cn];
      #pragma unroll
      for (int c=1;c<Cn;c++) m = fmaxf(m, sc[j*Cn+c]);
      float se = 0.0f, slab = 0.0f;
      #pragma unroll
      for (int c=0;c<Cn;c++){
        float v = sc[j*Cn+c];
        se += expf(v-m);
        if (c == label) slab = v;          // c is compile-time -> cndmask chain
      }
      float conf = logf(se) - (slab-m);
      cn[j] = (pos || ignored) ? 0.0f : conf;
      if (pos){
        posv += 1; confpv += conf;
        size_t bp = bp0 + j;
        float4 pc = ((const float4*)priors)[p0+j];
        float4 g  = ((const float4*)odm_locs)[bp];
        float cx = g.x*pc.z/10.0f + pc.x;
        float cy = g.y*pc.w/10.0f + pc.y;
        float w  = expf(g.z/5.0f)*pc.z;
        float h  = expf(g.w/5.0f)*pc.w;
        float dx1 = cx - w/2.0f, dy1 = cy - h/2.0f;
        float dx2 = cx + w/2.0f, dy2 = cy + h/2.0f;
        const float* gt = boxes + ((size_t)b*On + obj)*4;
        float gx1=gt[0], gy1=gt[1], gx2=gt[2], gy2=gt[3];
        float ltx=fmaxf(dx1,gx1), lty=fmaxf(dy1,gy1);
        float rbx=fminf(dx2,gx2), rby=fminf(dy2,gy2);
        float iw=fmaxf(rbx-ltx,0.0f), ih=fmaxf(rby-lty,0.0f);
        float inter=iw*ih;
        float ap=(dx2-dx1)*(dy2-dy1);
        float ag=(gx2-gx1)*(gy2-gy1);
        float iou = inter/((ap+ag)-inter);
        float cpx=(dx1+dx2)/2.0f, cpy=(dy1+dy2)/2.0f;
        float cgx=(gx1+gx2)/2.0f, cgy=(gy1+gy2)/2.0f;
        float ddx=cpx-cgx, ddy=cpy-cgy;
        float inter_diag = ddx*ddx + ddy*ddy;
        float cltx=fminf(dx1,gx1), clty=fminf(dy1,gy1);
        float crbx=fmaxf(dx2,gx2), crby=fmaxf(dy2,gy2);
        float odx=crbx-cltx, ody=crby-clty;
        float outer_diag = odx*odx + ody*ody;
        float diou = fminf(fmaxf(iou - inter_diag/outer_diag, -1.0f), 1.0f);
        locv += 1.0f - diou;
      }
    }
    *(float4*)(conf_neg + bp0) = make_float4(cn[0],cn[1],cn[2],cn[3]);
  }
  // per-wave butterfly reduction, lane 0 writes a unique slot -> zero contention
  #pragma unroll
  for (int d=32; d>0; d>>=1){
    locv   += __shfl_xor(locv,   d, 64);
    confpv += __shfl_xor(confpv, d, 64);
    posv   += __shfl_xor(posv,   d, 64);
    segv   += __shfl_xor(segv,   d, 64);
  }
  if ((t & 63) == 0){
    int widx = b*WPB + (blockIdx.x<<2) + (t>>6);
    ploc[widx]  = locv;
    pconf[widx] = confpv;
    ppos[widx]  = posv;
    pseg[widx]  = segv;
  }
}

// ---- phase E: 2-round radix select with per-bin (count,sum) ----
template<int ROUND>
__global__ void histE_kernel(const float* __restrict__ conf_neg,
                             const int* __restrict__ n_pos,
                             const unsigned* __restrict__ prefix,
                             const int* __restrict__ krem_st,
                             unsigned* __restrict__ gcnt,
                             float* __restrict__ gsum){
  int b = blockIdx.y, c = blockIdx.x, t = threadIdx.x;
  if (ROUND==1){
    if (n_pos[b] <= 0) return;
    if (krem_st[b] < 0) return;   // K>=Pn handled in scan0
  }
  __shared__ unsigned hc[4096];
  __shared__ float    hs[4096];
  for (int i=t;i<4096;i+=256){ hc[i]=0u; hs[i]=0.0f; }
  __syncthreads();
  unsigned pref = (ROUND==0)?0u:(prefix[b]>>20);
  const float* cn = conf_neg + (size_t)b*Pn;
  int p0 = c*CHUNK, p1 = min(Pn, p0+CHUNK);
  for (int p=p0+t; p<p1; p+=256){
    float v = cn[p];
    unsigned key = __float_as_uint(v);   // v >= 0 -> uint order == float order
    if (ROUND==0){
      unsigned d = key>>20;
      atomicAdd(&hc[d],1u); atomicAdd(&hs[d],v);
    } else {
      if ((key>>20)==pref){
        unsigned d = (key>>8)&0xFFFu;
        atomicAdd(&hc[d],1u); atomicAdd(&hs[d],v);
      }
    }
  }
  __syncthreads();
  unsigned* gc = gcnt + (size_t)b*4096;
  float*    gs = gsum + (size_t)b*4096;
  for (int i=t;i<4096;i+=256){
    if (hc[i]){ atomicAdd(&gc[i], hc[i]); atomicAdd(&gs[i], hs[i]); }
  }
}

template<int ROUND>
__global__ void scanE_kernel(const unsigned* __restrict__ gcnt,
                             const float* __restrict__ gsum,
                             const int* __restrict__ ppos,
                             int* __restrict__ n_pos,
                             unsigned* __restrict__ prefix,
                             int* __restrict__ krem_st,
                             double* __restrict__ stop0,
                             double* __restrict__ phard){
  int b = blockIdx.x, t = threadIdx.x;
  __shared__ unsigned sh[256];
  __shared__ int s_sel;
  __shared__ double sd[256];
  int K;
  if (ROUND==0){
    // fold n_pos reduce into scan0: sum this batch's WPB wave partials
    sh[t] = (t < WPB) ? (unsigned)ppos[b*WPB + t] : 0u;
    __syncthreads();
    for (int st=128; st>0; st>>=1){ if (t<st) sh[t]+=sh[t+st]; __syncthreads(); }
    if (t==0) n_pos[b] = (int)sh[0];
    K = 2*(int)sh[0];
    __syncthreads();
  } else {
    K = 2*n_pos[b];
  }
  if (K <= 0){ if (ROUND==0 && t==0){ phard[b] = 0.0; krem_st[b] = -1; } return; }
  if (ROUND==1 && krem_st[b] < 0) return;
  const unsigned* gc = gcnt + (size_t)b*4096;
  const float*    gs = gsum + (size_t)b*4096;
  unsigned cnt[16]; float sm[16];
  unsigned ts = 0;
  #pragma unroll
  for (int i=0;i<16;i++){ cnt[i]=gc[t*16+i]; sm[i]=gs[t*16+i]; ts+=cnt[i]; }
  if (t==0) s_sel = -1;
  sh[t]=ts;
  __syncthreads();
  for (int off=1; off<256; off<<=1){
    unsigned v = (t+off<256)? sh[t+off]:0u;   // read (after barrier)
    __syncthreads();
    sh[t]+=v;                                  // write
    __syncthreads();
  }
  if (ROUND==0 && K >= Pn){
    double ds=0.0;
    #pragma unroll
    for (int i=0;i<16;i++) ds += (double)sm[i];
    sd[t]=ds; __syncthreads();
    for (int st=128;st>0;st>>=1){ if(t<st) sd[t]+=sd[t+st]; __syncthreads(); }
    if (t==0){ phard[b]=sd[0]; krem_st[b]=-1; }
    return;
  }
  int krem = (ROUND==0)? K : krem_st[b];
  unsigned incl = sh[t];           // count of keys in bins >= this thread's lowest
  unsigned above = incl - ts;      // count in strictly-higher threads' bins
  if ((int)above < krem && krem <= (int)incl){
    int acc = (int)above;
    #pragma unroll
    for (int i=15;i>=0;i--){
      acc += (int)cnt[i];
      if (acc >= krem){
        unsigned sel = (unsigned)(t*16+i);
        int krem_new = krem - (acc - (int)cnt[i]);
        if (ROUND==0) prefix[b]  = sel<<20;
        else          prefix[b] |= sel<<8;
        krem_st[b] = krem_new;
        s_sel = (int)sel;
        break;
      }
    }
  }
  __syncthreads();
  int sel = s_sel;
  double ds = 0.0;
  #pragma unroll
  for (int i=0;i<16;i++){ int idx=t*16+i; if (idx > sel) ds += (double)sm[i]; }
  sd[t]=ds; __syncthreads();
  for (int st=128;st>0;st>>=1){ if(t<st) sd[t]+=sd[t+st]; __syncthreads(); }
  if (t==0){
    if (ROUND==0) stop0[b] = sd[0];
    else {
      // tie bucket approximated by its midpoint (error << absmax threshold)
      float vmid = __uint_as_float(prefix[b] | 0x80u);
      phard[b] = stop0[b] + sd[0] + (double)krem_st[b] * (double)vmid;
    }
  }
}

// ---- final combine: sum all partial arrays in doubles ----
__global__ void final_kernel(const int* __restrict__ n_pos,
                             const float* __restrict__ pseg,
                             const float* __restrict__ ploc,
                             const float* __restrict__ pconf,
                             const double* __restrict__ phard,
                             float* __restrict__ out){
  int t = threadIdx.x;
  double seg_s=0.0, loc_s=0.0, conf_s=0.0, hard_s=0.0;
  for (int i=t;i<Bn*WPB;i+=256)   seg_s  += (double)pseg[i];
  for (int i=t;i<Bn*WPB;i+=256)   loc_s  += (double)ploc[i];
  for (int i=t;i<Bn*WPB;i+=256)   conf_s += (double)pconf[i];
  for (int i=t;i<Bn;i+=256)       hard_s += phard[i];
  int tp_s = (t < Bn) ? n_pos[t] : 0;
  __shared__ double sd[256];
  __shared__ int    si_[256];
  si_[t]=tp_s;
  sd[t]=seg_s;  __syncthreads();
  for (int st=128;st>0;st>>=1){ if(t<st){ sd[t]+=sd[t+st]; si_[t]+=si_[t+st]; } __syncthreads(); }
  double seg_t = sd[0]; int tp = si_[0];
  __syncthreads();
  sd[t]=loc_s;  __syncthreads();
  for (int st=128;st>0;st>>=1){ if(t<st) sd[t]+=sd[t+st]; __syncthreads(); }
  double loc_t = sd[0];
  __syncthreads();
  sd[t]=conf_s+hard_s; __syncthreads();
  for (int st=128;st>0;st>>=1){ if(t<st) sd[t]+=sd[t+st]; __syncthreads(); }
  double conf_t = sd[0];
  if (t==0){
    float total = (float)tp;
    float conf_loss = (float)conf_t / total;
    float loc_loss  = (float)loc_t / total;
    float seg_loss  = -(float)seg_t;
    out[0] = conf_loss + loc_loss + seg_loss;
  }
}

extern "C" void kernel_launch(void* const* d_in, const int* in_sizes, int n_in,
                              void* d_out, int out_size, void* d_ws, size_t ws_size,
                              hipStream_t stream) {
  const float* odm_locs   = (const float*)d_in[0];
  const float* odm_scores = (const float*)d_in[1];
  const float* att        = (const float*)d_in[2];
  const float* boxes      = (const float*)d_in[3];
  const int*   labels     = (const int*)d_in[4];
  const float* ign        = (const float*)d_in[5];
  const float* priors     = (const float*)d_in[6];
  float* out = (float*)d_out;

  size_t np = (size_t)Bn * Pn;
  float* ov_prior  = (float*)d_ws;                 // B*P f32
  int*   objinfo   = (int*)(ov_prior + np);        // B*P i32
  float* conf_neg  = (float*)(objinfo + np);       // B*P f32
  unsigned long long* key_obj = (unsigned long long*)(conf_neg + np); // B*O u64
  double* phard    = (double*)(key_obj + (size_t)Bn*On); // Bn f64
  int*    n_pos    = (int*)(phard + Bn);                 // B i32
  float*  pseg     = (float*)(n_pos + Bn);               // B*WPB f32
  float*  ploc     = pseg + (size_t)Bn*WPB;              // B*WPB f32
  float*  pconf    = ploc + (size_t)Bn*WPB;              // B*WPB f32
  int*    ppos     = (int*)(pconf + (size_t)Bn*WPB);     // B*WPB i32

  // radix-select scratch in the ov_prior region (dead after phaseD):
  unsigned* gcnt0 = (unsigned*)ov_prior;
  float*    gsum0 = (float*)(gcnt0 + (size_t)Bn*4096);
  unsigned* gcnt1 = (unsigned*)(gsum0 + (size_t)Bn*4096);
  float*    gsum1 = (float*)(gcnt1 + (size_t)Bn*4096);
  unsigned* prefix = (unsigned*)(gsum1 + (size_t)Bn*4096);
  int*      krem   = (int*)(prefix + Bn);
  double*   stop0  = (double*)(krem + Bn);   // 8B-aligned

  // only key_obj needs zeroing (atomicMax targets); partials fully written
  hipMemsetAsync(key_obj, 0, (size_t)Bn*On*8, stream);

  matchAB_kernel<<<dim3(FBLK, Bn), 256, 0, stream>>>(boxes, ign, priors,
                                                     ov_prior, objinfo, key_obj);
  phaseC_kernel<<<Bn, 64, 0, stream>>>(key_obj, ov_prior, objinfo);
  phaseD_kernel<<<dim3(DBLK, Bn), 256, 0, stream>>>(odm_locs, odm_scores, boxes, labels,
                                                    priors, ov_prior, objinfo, att,
                                                    conf_neg, ploc, pconf, ppos, pseg);
  // ov_prior dead from here; reuse as radix scratch
  hipMemsetAsync(gcnt0, 0, 4*(size_t)Bn*4096*sizeof(unsigned), stream);
  histE_kernel<0><<<dim3(CHn, Bn), 256, 0, stream>>>(conf_neg, n_pos, prefix, krem, gcnt0, gsum0);
  scanE_kernel<0><<<Bn, 256, 0, stream>>>(gcnt0, gsum0, ppos, n_pos, prefix, krem, stop0, phard);
  histE_kernel<1><<<dim3(CHn, Bn), 256, 0, stream>>>(conf_neg, n_pos, prefix, krem, gcnt1, gsum1);
  scanE_kernel<1><<<Bn, 256, 0, stream>>>(gcnt1, gsum1, ppos, n_pos, prefix, krem, stop0, phard);
  final_kernel<<<1, 256, 0, stream>>>(n_pos, pseg, ploc, pconf, phard, out);
}

// Round 23
// 156.254 us; speedup vs baseline: 1.4564x; 1.1268x over previous
//
#include <hip/hip_runtime.h>
#include <math.h>

#define Bn 32
#define Pn 42840
#define On 64
#define NIn 8
#define Cn 11
#define ATT_N (32*56*96)
#define THRESHOLD_F 0.4f
#define THETA_F 0.1f
#define CHn 16
#define CHUNK ((Pn + CHn - 1)/CHn)
#define DBLK 42         /* phaseD blocks per batch */
#define WPB  (DBLK*4)   /* phaseD waves per batch = 168 */
#define FP 4            /* priors per thread in matchAB */
#define FBLK ((Pn + 256*FP - 1)/(256*FP))   /* 42 blocks per batch */

// opaque register pin: read-write empty asm -> compiler cannot rematerialize
#define PINF(x) asm volatile("" : "+v"(x))

// ---- fused match: ONE pass over the O x P iou matrix reduces BOTH axes ----
__global__ void __launch_bounds__(256, 4)
matchAB_kernel(const float* __restrict__ boxes,
               const float* __restrict__ ign,
               const float* __restrict__ priors,
               float* __restrict__ ov_prior,
               int* __restrict__ objinfo,
               unsigned long long* __restrict__ key_obj){
  __shared__ float4 sbox[On];
  __shared__ float  sar[On];
  __shared__ float4 ibox[NIn];
  __shared__ float  iar[NIn];
  __shared__ unsigned long long skey[On];
  int b = blockIdx.y, t = threadIdx.x;
  if (t < On){
    float4 v = ((const float4*)boxes)[b*On + t];
    sbox[t]=v; sar[t]=(v.z-v.x)*(v.w-v.y);
    skey[t]=0ull;
  } else if (t < On+NIn){
    int o = t - On;
    float4 v = ((const float4*)ign)[b*NIn + o];
    ibox[o]=v; iar[o]=(v.z-v.x)*(v.w-v.y);
  }
  __syncthreads();
  int p0 = (blockIdx.x*256 + t)*FP;
  bool active = (p0 < Pn);          // Pn%4==0 -> all 4 valid when active
  float px1[FP], py1[FP], px2[FP], py2[FP], pab[FP];
  #pragma unroll
  for (int q=0;q<FP;q++){
    float4 pc = active ? ((const float4*)priors)[p0+q]
                       : make_float4(0.f,0.f,0.f,0.f);
    px1[q]=pc.x - pc.z*0.5f; py1[q]=pc.y - pc.w*0.5f;
    px2[q]=pc.x + pc.z*0.5f; py2[q]=pc.y + pc.w*0.5f;
    pab[q]=(px2[q]-px1[q])*(py2[q]-py1[q]);
    PINF(px1[q]); PINF(py1[q]); PINF(px2[q]); PINF(py2[q]); PINF(pab[q]);
  }
  float best[FP]; int bo[FP];
  #pragma unroll
  for (int q=0;q<FP;q++){ best[q]=-1.0f; bo[q]=0; }
  #pragma unroll 1
  for (int o=0;o<On;o++){
    float4 ob = sbox[o];
    float oar = sar[o];
    float cmax=-1.0f; unsigned cp=0u;
    #pragma unroll
    for (int q=0;q<FP;q++){
      float ltx=fmaxf(ob.x,px1[q]), lty=fmaxf(ob.y,py1[q]);
      float rbx=fminf(ob.z,px2[q]), rby=fminf(ob.w,py2[q]);
      float w=fmaxf(rbx-ltx,0.0f), h=fmaxf(rby-lty,0.0f);
      float inter=w*h;
      float uni=(oar+pab[q])-inter;
      float iou = inter * __builtin_amdgcn_rcpf(uni);
      if (iou > best[q]){ best[q]=iou; bo[q]=o; }   // row argmax, first-occurrence
      if (iou > cmax){ cmax=iou; cp=(unsigned)(p0+q); } // col local, smallest p
    }
    // float-only wave max, then lowest-lane-among-ties = smallest p
    float wm = cmax;
    #pragma unroll
    for (int d=32; d>0; d>>=1)
      wm = fmaxf(wm, __shfl_xor(wm, d, 64));
    unsigned long long ball = __ballot(cmax == wm);
    int leader = __ffsll((long long)ball) - 1;
    if (active && (t & 63) == leader){
      unsigned long long key = ((unsigned long long)__float_as_uint(wm)<<32)
                             | (unsigned long long)(0xFFFFFFFFu - cp);
      atomicMax(&skey[o], key);
    }
  }
  // ignored regions: per-prior max only
  float ib[FP];
  #pragma unroll
  for (int q=0;q<FP;q++) ib[q]=-1.0f;
  #pragma unroll
  for (int j=0;j<NIn;j++){
    float4 jb = ibox[j];
    float jar = iar[j];
    #pragma unroll
    for (int q=0;q<FP;q++){
      float ltx=fmaxf(jb.x,px1[q]), lty=fmaxf(jb.y,py1[q]);
      float rbx=fminf(jb.z,px2[q]), rby=fminf(jb.w,py2[q]);
      float w=fmaxf(rbx-ltx,0.0f), h=fmaxf(rby-lty,0.0f);
      float inter=w*h;
      float uni=(jar+pab[q])-inter;
      ib[q] = fmaxf(ib[q], inter * __builtin_amdgcn_rcpf(uni));
    }
  }
  if (active){
    size_t bp0 = (size_t)b*Pn + p0;
    int in_[FP];
    #pragma unroll
    for (int q=0;q<FP;q++)
      in_[q] = bo[q] | ((ib[q] >= THETA_F) ? 256 : 0);
    *(float4*)(ov_prior + bp0) = make_float4(best[0],best[1],best[2],best[3]);
    *(int4*)(objinfo + bp0)    = make_int4(in_[0],in_[1],in_[2],in_[3]);
  }
  __syncthreads();
  if (t < On) atomicMax(&key_obj[(size_t)b*On + t], skey[t]);
}

// ---- phase D: 4 priors/thread + folded seg + fused phaseC winner-list ----
__global__ void __launch_bounds__(256, 4)
phaseD_kernel(const float* __restrict__ odm_locs,
              const float* __restrict__ odm_scores,
              const float* __restrict__ boxes,
              const int* __restrict__ labels,
              const float* __restrict__ priors,
              const float* __restrict__ ov_prior,
              const int* __restrict__ objinfo,
              const float* __restrict__ att,
              const unsigned long long* __restrict__ key_obj,
              float* __restrict__ conf_neg,
              float* __restrict__ ploc,
              float* __restrict__ pconf,
              int* __restrict__ ppos,
              float* __restrict__ pseg){
  int b = blockIdx.y;
  int t = threadIdx.x;
  // winner list for this block's prior range [pbase, pbase+1024)
  __shared__ int wl_p[On];
  __shared__ int wl_rank[On];
  __shared__ int wl_n;
  int pbase = blockIdx.x*1024;
  if (t == 0) wl_n = 0;
  __syncthreads();
  if (t < On){                          // first wave only
    unsigned long long k = key_obj[(size_t)b*On + t];
    bool valid = (unsigned)(k>>32) > 0u;
    unsigned long long ball = __ballot(valid);
    int rank = (int)__popcll(ball & ((1ull<<t) - 1ull));  // cumsum(valid)-1
    if (valid){
      int p = (int)(0xFFFFFFFFu - (unsigned)(k & 0xFFFFFFFFu));
      if (p >= pbase && p < pbase + 1024){
        int idx = atomicAdd(&wl_n, 1);
        wl_p[idx] = p; wl_rank[idx] = rank;
      }
    }
  }
  // folded seg: phaseD has 1344*256 = 344064 threads >= ATT_N = 172032
  int gid = (b*DBLK + blockIdx.x)*256 + t;
  float segv = 0.0f;
  if (gid < ATT_N) segv = fmaxf(log1pf(-att[gid]), -100.0f);
  __syncthreads();
  int nwl = wl_n;
  int p0 = pbase + t*4;
  float locv = 0.0f, confpv = 0.0f; int posv = 0;
  if (p0 < Pn){                           // Pn%4==0 -> all 4 priors valid
    size_t bp0 = (size_t)b*Pn + p0;
    float4 sc4[11];
    const float4* src = (const float4*)(odm_scores + bp0*Cn);  // 16B-aligned
    #pragma unroll
    for (int i=0;i<11;i++) sc4[i] = src[i];
    int4   info4 = *(const int4*)(objinfo + bp0);
    float4 ovp4  = *(const float4*)(ov_prior + bp0);
    const float* sc = (const float*)sc4;   // constant indices only (post-unroll)
    float cn[4];
    #pragma unroll
    for (int j=0;j<4;j++){
      int info = (&info4.x)[j];
      int obj = info & 0xFF;
      bool ignored = (info & 256) != 0;
      float ov = (&ovp4.x)[j];
      // winner override: obj -> rank (max over duplicates == last-write-wins), ov -> 1.0
      int ovr = -1;
      for (int i=0;i<nwl;i++)
        if (wl_p[i] == p0+j) ovr = max(ovr, wl_rank[i]);
      if (ovr >= 0){ obj = ovr; ov = 1.0f; }
      int label = labels[b*On + obj];
      if (ov < THRESHOLD_F) label = 0;
      bool pos = label > 0;
      float m = sc[j*Cn];
      #pragma unroll
      for (int c=1;c<Cn;c++) m = fmaxf(m, sc[j*Cn+c]);
      float se = 0.0f, slab = 0.0f;
      #pragma unroll
      for (int c=0;c<Cn;c++){
        float v = sc[j*Cn+c];
        se += expf(v-m);
        if (c == label) slab = v;          // c is compile-time -> cndmask chain
      }
      float conf = logf(se) - (slab-m);
      cn[j] = (pos || ignored) ? 0.0f : conf;
      if (pos){
        posv += 1; confpv += conf;
        size_t bp = bp0 + j;
        float4 pc = ((const float4*)priors)[p0+j];
        float4 g  = ((const float4*)odm_locs)[bp];
        float cx = g.x*pc.z/10.0f + pc.x;
        float cy = g.y*pc.w/10.0f + pc.y;
        float w  = expf(g.z/5.0f)*pc.z;
        float h  = expf(g.w/5.0f)*pc.w;
        float dx1 = cx - w/2.0f, dy1 = cy - h/2.0f;
        float dx2 = cx + w/2.0f, dy2 = cy + h/2.0f;
        const float* gt = boxes + ((size_t)b*On + obj)*4;
        float gx1=gt[0], gy1=gt[1], gx2=gt[2], gy2=gt[3];
        float ltx=fmaxf(dx1,gx1), lty=fmaxf(dy1,gy1);
        float rbx=fminf(dx2,gx2), rby=fminf(dy2,gy2);
        float iw=fmaxf(rbx-ltx,0.0f), ih=fmaxf(rby-lty,0.0f);
        float inter=iw*ih;
        float ap=(dx2-dx1)*(dy2-dy1);
        float ag=(gx2-gx1)*(gy2-gy1);
        float iou = inter/((ap+ag)-inter);
        float cpx=(dx1+dx2)/2.0f, cpy=(dy1+dy2)/2.0f;
        float cgx=(gx1+gx2)/2.0f, cgy=(gy1+gy2)/2.0f;
        float ddx=cpx-cgx, ddy=cpy-cgy;
        float inter_diag = ddx*ddx + ddy*ddy;
        float cltx=fminf(dx1,gx1), clty=fminf(dy1,gy1);
        float crbx=fmaxf(dx2,gx2), crby=fmaxf(dy2,gy2);
        float odx=crbx-cltx, ody=crby-clty;
        float outer_diag = odx*odx + ody*ody;
        float diou = fminf(fmaxf(iou - inter_diag/outer_diag, -1.0f), 1.0f);
        locv += 1.0f - diou;
      }
    }
    *(float4*)(conf_neg + bp0) = make_float4(cn[0],cn[1],cn[2],cn[3]);
  }
  // per-wave butterfly reduction, lane 0 writes a unique slot -> zero contention
  #pragma unroll
  for (int d=32; d>0; d>>=1){
    locv   += __shfl_xor(locv,   d, 64);
    confpv += __shfl_xor(confpv, d, 64);
    posv   += __shfl_xor(posv,   d, 64);
    segv   += __shfl_xor(segv,   d, 64);
  }
  if ((t & 63) == 0){
    int widx = b*WPB + (blockIdx.x<<2) + (t>>6);
    ploc[widx]  = locv;
    pconf[widx] = confpv;
    ppos[widx]  = posv;
    pseg[widx]  = segv;
  }
}

// ---- phase E: SINGLE-round 12-bit radix select with per-bin (count,sum) ----
// tie bin approximated by its midpoint; output error divided by total_pos
__global__ void histE_kernel(const float* __restrict__ conf_neg,
                             unsigned* __restrict__ gcnt,
                             float* __restrict__ gsum){
  int b = blockIdx.y, c = blockIdx.x, t = threadIdx.x;
  __shared__ unsigned hc[4096];
  __shared__ float    hs[4096];
  for (int i=t;i<4096;i+=256){ hc[i]=0u; hs[i]=0.0f; }
  __syncthreads();
  const float* cn = conf_neg + (size_t)b*Pn;
  int p0 = c*CHUNK, p1 = min(Pn, p0+CHUNK);
  for (int p=p0+t; p<p1; p+=256){
    float v = cn[p];
    unsigned d = __float_as_uint(v)>>20;   // v >= 0 -> uint order == float order
    atomicAdd(&hc[d],1u); atomicAdd(&hs[d],v);
  }
  __syncthreads();
  unsigned* gc = gcnt + (size_t)b*4096;
  float*    gs = gsum + (size_t)b*4096;
  for (int i=t;i<4096;i+=256){
    if (hc[i]){ atomicAdd(&gc[i], hc[i]); atomicAdd(&gs[i], hs[i]); }
  }
}

__global__ void scanE_kernel(const unsigned* __restrict__ gcnt,
                             const float* __restrict__ gsum,
                             const int* __restrict__ ppos,
                             int* __restrict__ n_pos,
                             double* __restrict__ phard){
  int b = blockIdx.x, t = threadIdx.x;
  __shared__ unsigned sh[256];
  __shared__ int s_sel, s_krem;
  __shared__ double sd[256];
  // fold n_pos reduce: sum this batch's WPB wave partials
  sh[t] = (t < WPB) ? (unsigned)ppos[b*WPB + t] : 0u;
  __syncthreads();
  for (int st=128; st>0; st>>=1){ if (t<st) sh[t]+=sh[t+st]; __syncthreads(); }
  if (t==0) n_pos[b] = (int)sh[0];
  int K = 2*(int)sh[0];
  __syncthreads();
  if (K <= 0){ if (t==0) phard[b] = 0.0; return; }
  const unsigned* gc = gcnt + (size_t)b*4096;
  const float*    gs = gsum + (size_t)b*4096;
  unsigned cnt[16]; float sm[16];
  unsigned ts = 0;
  #pragma unroll
  for (int i=0;i<16;i++){ cnt[i]=gc[t*16+i]; sm[i]=gs[t*16+i]; ts+=cnt[i]; }
  if (t==0){ s_sel = -1; s_krem = 0; }
  sh[t]=ts;
  __syncthreads();
  for (int off=1; off<256; off<<=1){
    unsigned v = (t+off<256)? sh[t+off]:0u;   // read (after barrier)
    __syncthreads();
    sh[t]+=v;                                  // write
    __syncthreads();
  }
  if (K >= Pn){
    double ds=0.0;
    #pragma unroll
    for (int i=0;i<16;i++) ds += (double)sm[i];
    sd[t]=ds; __syncthreads();
    for (int st=128;st>0;st>>=1){ if(t<st) sd[t]+=sd[t+st]; __syncthreads(); }
    if (t==0) phard[b]=sd[0];
    return;
  }
  unsigned incl = sh[t];           // count of keys in bins >= this thread's lowest
  unsigned above = incl - ts;      // count in strictly-higher threads' bins
  if ((int)above < K && K <= (int)incl){
    int acc = (int)above;
    #pragma unroll
    for (int i=15;i>=0;i--){
      acc += (int)cnt[i];
      if (acc >= K){
        s_sel  = t*16 + i;
        s_krem = K - (acc - (int)cnt[i]);
        break;
      }
    }
  }
  __syncthreads();
  int sel = s_sel;
  double ds = 0.0;
  #pragma unroll
  for (int i=0;i<16;i++){ int idx=t*16+i; if (idx > sel) ds += (double)sm[i]; }
  sd[t]=ds; __syncthreads();
  for (int st=128;st>0;st>>=1){ if(t<st) sd[t]+=sd[t+st]; __syncthreads(); }
  if (t==0){
    // tie bin approximated by its midpoint (bounded error, / total_pos in output)
    float vmid = __uint_as_float(((unsigned)sel<<20) | 0x80000u);
    phard[b] = sd[0] + (double)s_krem * (double)vmid;
  }
}

// ---- final combine: sum all partial arrays in doubles ----
__global__ void final_kernel(const int* __restrict__ n_pos,
                             const float* __restrict__ pseg,
                             const float* __restrict__ ploc,
                             const float* __restrict__ pconf,
                             const double* __restrict__ phard,
                             float* __restrict__ out){
  int t = threadIdx.x;
  double seg_s=0.0, loc_s=0.0, conf_s=0.0, hard_s=0.0;
  for (int i=t;i<Bn*WPB;i+=256)   seg_s  += (double)pseg[i];
  for (int i=t;i<Bn*WPB;i+=256)   loc_s  += (double)ploc[i];
  for (int i=t;i<Bn*WPB;i+=256)   conf_s += (double)pconf[i];
  for (int i=t;i<Bn;i+=256)       hard_s += phard[i];
  int tp_s = (t < Bn) ? n_pos[t] : 0;
  __shared__ double sd[256];
  __shared__ int    si_[256];
  si_[t]=tp_s;
  sd[t]=seg_s;  __syncthreads();
  for (int st=128;st>0;st>>=1){ if(t<st){ sd[t]+=sd[t+st]; si_[t]+=si_[t+st]; } __syncthreads(); }
  double seg_t = sd[0]; int tp = si_[0];
  __syncthreads();
  sd[t]=loc_s;  __syncthreads();
  for (int st=128;st>0;st>>=1){ if(t<st) sd[t]+=sd[t+st]; __syncthreads(); }
  double loc_t = sd[0];
  __syncthreads();
  sd[t]=conf_s+hard_s; __syncthreads();
  for (int st=128;st>0;st>>=1){ if(t<st) sd[t]+=sd[t+st]; __syncthreads(); }
  double conf_t = sd[0];
  if (t==0){
    float total = (float)tp;
    float conf_loss = (float)conf_t / total;
    float loc_loss  = (float)loc_t / total;
    float seg_loss  = -(float)seg_t;
    out[0] = conf_loss + loc_loss + seg_loss;
  }
}

extern "C" void kernel_launch(void* const* d_in, const int* in_sizes, int n_in,
                              void* d_out, int out_size, void* d_ws, size_t ws_size,
                              hipStream_t stream) {
  const float* odm_locs   = (const float*)d_in[0];
  const float* odm_scores = (const float*)d_in[1];
  const float* att        = (const float*)d_in[2];
  const float* boxes      = (const float*)d_in[3];
  const int*   labels     = (const int*)d_in[4];
  const float* ign        = (const float*)d_in[5];
  const float* priors     = (const float*)d_in[6];
  float* out = (float*)d_out;

  size_t np = (size_t)Bn * Pn;
  float* ov_prior  = (float*)d_ws;                 // B*P f32
  int*   objinfo   = (int*)(ov_prior + np);        // B*P i32
  float* conf_neg  = (float*)(objinfo + np);       // B*P f32
  unsigned long long* key_obj = (unsigned long long*)(conf_neg + np); // B*O u64
  double* phard    = (double*)(key_obj + (size_t)Bn*On); // Bn f64
  int*    n_pos    = (int*)(phard + Bn);                 // B i32
  float*  pseg     = (float*)(n_pos + Bn);               // B*WPB f32
  float*  ploc     = pseg + (size_t)Bn*WPB;              // B*WPB f32
  float*  pconf    = ploc + (size_t)Bn*WPB;              // B*WPB f32
  int*    ppos     = (int*)(pconf + (size_t)Bn*WPB);     // B*WPB i32

  // radix-select scratch in the ov_prior region (dead after phaseD):
  unsigned* gcnt0 = (unsigned*)ov_prior;
  float*    gsum0 = (float*)(gcnt0 + (size_t)Bn*4096);

  // only key_obj needs zeroing (atomicMax targets); partials fully written
  hipMemsetAsync(key_obj, 0, (size_t)Bn*On*8, stream);

  matchAB_kernel<<<dim3(FBLK, Bn), 256, 0, stream>>>(boxes, ign, priors,
                                                     ov_prior, objinfo, key_obj);
  phaseD_kernel<<<dim3(DBLK, Bn), 256, 0, stream>>>(odm_locs, odm_scores, boxes, labels,
                                                    priors, ov_prior, objinfo, att, key_obj,
                                                    conf_neg, ploc, pconf, ppos, pseg);
  // ov_prior dead from here; reuse as radix scratch (stream-ordered after phaseD)
  hipMemsetAsync(gcnt0, 0, 2*(size_t)Bn*4096*sizeof(unsigned), stream);
  histE_kernel<<<dim3(CHn, Bn), 256, 0, stream>>>(conf_neg, gcnt0, gsum0);
  scanE_kernel<<<Bn, 256, 0, stream>>>(gcnt0, gsum0, ppos, n_pos, phard);
  final_kernel<<<1, 256, 0, stream>>>(n_pos, pseg, ploc, pconf, phard, out);
}